// Round 6
// baseline (627.516 us; speedup 1.0000x reference)
//
#include <hip/hip_runtime.h>
#include <hip/hip_bf16.h>

// Problem constants (fixed by the reference)
#define DD   768
#define TT   1024
#define BBATCH 16
#define NROWS (BBATCH * TT)   // 16384
#define HIDN 3072
#define HHALF 1536
#define HH 32
#define WW 32
#define DW  (DD * DD)         // 589824
#define DH  (DD * HIDN)       // 2359296
#define CCH 64                // wkv chunk length
#define PCH (TT / CCH)        // 16 chunks

typedef float  floatx4 __attribute__((ext_vector_type(4)));
typedef __bf16 bf16x8  __attribute__((ext_vector_type(8)));

__device__ __forceinline__ float bf2f(__hip_bfloat16 v) { return __bfloat162float(v); }
__device__ __forceinline__ __hip_bfloat16 f2bf(float v) { return __float2bfloat16(v); }
__device__ __forceinline__ float toF(__hip_bfloat16 v) { return __bfloat162float(v); }
__device__ __forceinline__ float toF(float v) { return v; }

__device__ __forceinline__ void load4f(const float* __restrict__ p, float o[4]) {
    const float4 v = *reinterpret_cast<const float4*>(p);
    o[0] = v.x; o[1] = v.y; o[2] = v.z; o[3] = v.w;
}
__device__ __forceinline__ void load4f(const __hip_bfloat16* __restrict__ p, float o[4]) {
    const ushort4 v = *reinterpret_cast<const ushort4*>(p);
    o[0] = bf2f(__hip_bfloat16_raw{v.x});
    o[1] = bf2f(__hip_bfloat16_raw{v.y});
    o[2] = bf2f(__hip_bfloat16_raw{v.z});
    o[3] = bf2f(__hip_bfloat16_raw{v.w});
}
__device__ __forceinline__ void load8f(const float* __restrict__ p, float o[8]) {
    load4f(p, o); load4f(p + 4, o + 4);
}
__device__ __forceinline__ void load8f(const __hip_bfloat16* __restrict__ p, float o[8]) {
    const uint4 v = *reinterpret_cast<const uint4*>(p);
    const unsigned short* s = reinterpret_cast<const unsigned short*>(&v);
#pragma unroll
    for (int e = 0; e < 8; ++e) o[e] = bf2f(__hip_bfloat16_raw{s[e]});
}

// global -> LDS direct DMA, 16 B per lane, dest = uniform base + lane*16
#define GL2LDS(gp, lp)  __builtin_amdgcn_global_load_lds(                     \
    (const __attribute__((address_space(1))) void*)(gp),                      \
    (__attribute__((address_space(3))) void*)(lp), 16, 0, 0)

#define BARX() __builtin_amdgcn_s_barrier()
#define WAITV6() do { asm volatile("s_waitcnt vmcnt(6)");                      \
    __builtin_amdgcn_sched_barrier(0); } while (0)
#define WAITV0() do { asm volatile("s_waitcnt vmcnt(0)");                      \
    __builtin_amdgcn_sched_barrier(0); } while (0)

// ---------------------------------------------------------------------------
// fp32 -> bf16 conversion of ALL weights in one dispatch (7 segments).
// ---------------------------------------------------------------------------
__global__ __launch_bounds__(256)
void cvt_all(const float* __restrict__ w0, const float* __restrict__ w1,
             const float* __restrict__ w2, const float* __restrict__ w3,
             const float* __restrict__ w4, const float* __restrict__ w5,
             const float* __restrict__ w6, __hip_bfloat16* __restrict__ dst)
{
    const int b = blockIdx.x;
    const float* s; size_t dofs; int rel;
    if (b < 2880) {            // 5 x 576 blocks of DW
        const int seg = b / 576; rel = b - seg * 576;
        s = seg == 0 ? w0 : seg == 1 ? w1 : seg == 2 ? w2 : seg == 3 ? w3 : w4;
        dofs = (size_t)seg * DW;
    } else if (b < 5184) {     // Ck
        rel = b - 2880; s = w5; dofs = 5ull * DW;
    } else {                   // Cv
        rel = b - 5184; s = w6; dofs = 5ull * DW + DH;
    }
    const int i = rel * 1024 + threadIdx.x * 4;
    const float4 v = *reinterpret_cast<const float4*>(s + i);
    __hip_bfloat16 o[4] = {f2bf(v.x), f2bf(v.y), f2bf(v.z), f2bf(v.w)};
    *reinterpret_cast<ushort4*>(&dst[dofs + i]) = *reinterpret_cast<const ushort4*>(o);
}

// ---------------------------------------------------------------------------
// Per-row LN stats: one wave per row, vectorized.
// ---------------------------------------------------------------------------
template <typename TIN>
__global__ __launch_bounds__(256)
void ln_stats_k(const TIN* __restrict__ x,
                float* __restrict__ mean, float* __restrict__ rstd)
{
    const int row  = blockIdx.x * 4 + (threadIdx.x >> 6);
    const int lane = threadIdx.x & 63;
    const TIN* xr = x + (size_t)row * DD;
    float s1 = 0.f, s2 = 0.f;
#pragma unroll
    for (int q = 0; q < 3; ++q) {
        float v4[4];
        load4f(xr + 4 * lane + 256 * q, v4);
#pragma unroll
        for (int e = 0; e < 4; ++e) { s1 += v4[e]; s2 += v4[e] * v4[e]; }
    }
#pragma unroll
    for (int off = 32; off > 0; off >>= 1) {
        s1 += __shfl_down(s1, off);
        s2 += __shfl_down(s2, off);
    }
    if (lane == 0) {
        const float m = s1 * (1.f / DD);
        mean[row] = m;
        rstd[row] = rsqrtf(s2 * (1.f / DD) - m * m + 1e-5f);
    }
}

// ---------------------------------------------------------------------------
// LN-on-the-fly + q_shift + token-mix, 8 channels/thread (uint4 bf16 stores).
// ---------------------------------------------------------------------------
template <typename TIN, int NOUT>
__global__ __launch_bounds__(256)
void mix_k(const TIN* __restrict__ x,
           const float* __restrict__ mean, const float* __restrict__ rstd,
           const float* __restrict__ g, const float* __restrict__ b,
           const float* __restrict__ muk,
           const float* __restrict__ muv,
           const float* __restrict__ mur,
           __hip_bfloat16* __restrict__ xk,
           __hip_bfloat16* __restrict__ xv,
           __hip_bfloat16* __restrict__ xr)
{
    const size_t i8 = ((size_t)blockIdx.x * 256 + threadIdx.x) * 8;
    const int c  = (int)(i8 % DD);
    const int n  = (int)((i8 / DD) % TT);
    const int bb = (int)(i8 / ((size_t)DD * TT));
    const int y = n >> 5, xp = n & 31;
    const int grow = bb * TT + n;

    const int grp = c / (DD / 4);
    int ny = y, nx = xp; bool ok;
    if      (grp == 0) { nx = xp - 1; ok = xp > 0;      }
    else if (grp == 1) { nx = xp + 1; ok = xp < WW - 1; }
    else if (grp == 2) { ny = y - 1;  ok = y > 0;       }
    else               { ny = y + 1;  ok = y < HH - 1;  }

    float gg[8], bbv[8];
    load8f(g + c, gg); load8f(b + c, bbv);

    float xc[8];
    load8f(x + (size_t)grow * DD + c, xc);
    const float m = mean[grow], rs = rstd[grow];
    float av[8], sx[8] = {0.f, 0.f, 0.f, 0.f, 0.f, 0.f, 0.f, 0.f};
#pragma unroll
    for (int e = 0; e < 8; ++e) av[e] = (xc[e] - m) * rs * gg[e] + bbv[e];

    if (ok) {
        const int nrow = bb * TT + ny * WW + nx;
        float xn[8];
        load8f(x + (size_t)nrow * DD + c, xn);
        const float m2 = mean[nrow], rs2 = rstd[nrow];
#pragma unroll
        for (int e = 0; e < 8; ++e) sx[e] = (xn[e] - m2) * rs2 * gg[e] + bbv[e];
    }

    float mk[8], mr[8];
    load8f(muk + c, mk); load8f(mur + c, mr);
    __hip_bfloat16 ok8[8], or8[8];
#pragma unroll
    for (int e = 0; e < 8; ++e) {
        ok8[e] = f2bf(av[e] * mk[e] + sx[e] * (1.f - mk[e]));
        or8[e] = f2bf(av[e] * mr[e] + sx[e] * (1.f - mr[e]));
    }
    *reinterpret_cast<uint4*>(&xk[i8]) = *reinterpret_cast<const uint4*>(ok8);
    *reinterpret_cast<uint4*>(&xr[i8]) = *reinterpret_cast<const uint4*>(or8);
    if (NOUT == 3) {
        float mv[8];
        load8f(muv + c, mv);
        __hip_bfloat16 ov8[8];
#pragma unroll
        for (int e = 0; e < 8; ++e)
            ov8[e] = f2bf(av[e] * mv[e] + sx[e] * (1.f - mv[e]));
        *reinterpret_cast<uint4*>(&xv[i8]) = *reinterpret_cast<const uint4*>(ov8);
    }
}

// ---------------------------------------------------------------------------
// Shared epilogue transpose + MODE stores
// ---------------------------------------------------------------------------
__device__ __forceinline__ void xpose_band(const floatx4 accRow[4], float* scr,
                                           int lane, float cv[16])
{
    const int l15 = lane & 15, quad = lane >> 4;
#pragma unroll
    for (int j = 0; j < 4; ++j)
#pragma unroll
        for (int r = 0; r < 4; ++r)
            scr[(quad * 4 + r) * 68 + j * 16 + l15] = accRow[j][r];
    const int row_l = lane >> 2, cb = (lane & 3) * 16;
#pragma unroll
    for (int q = 0; q < 4; ++q)
        *reinterpret_cast<float4*>(&cv[q * 4]) =
            *reinterpret_cast<const float4*>(&scr[row_l * 68 + cb + q * 4]);
}

// MODE: 1=bf16(sigmoid), 2=bf16(acc + xf32), 3=bf16(relu^2),
//       4=f32 out = h + s*acc + x   (s bf16)
//       5=f32 out += s*acc
//       6=f32 out = h + gf*acc + x  (gf fp32; may alias out — own tile only)
//       7=f32 out = sigmoid(acc)
template <int MODE>
__device__ __forceinline__ void mode_store(
    const float cv[16], size_t idx,
    __hip_bfloat16* __restrict__ outB, float* __restrict__ outF,
    const __hip_bfloat16* __restrict__ auxS, const __hip_bfloat16* __restrict__ auxH,
    const float* __restrict__ auxX, const float* __restrict__ auxG)
{
    if (MODE == 1 || MODE == 3) {
        __hip_bfloat16 ob[16];
#pragma unroll
        for (int e = 0; e < 16; ++e) {
            float v = cv[e];
            if (MODE == 1) v = 1.f / (1.f + __expf(-v));
            else { v = fmaxf(v, 0.f); v = v * v; }
            ob[e] = f2bf(v);
        }
        *reinterpret_cast<uint4*>(&outB[idx])     = *reinterpret_cast<const uint4*>(&ob[0]);
        *reinterpret_cast<uint4*>(&outB[idx + 8]) = *reinterpret_cast<const uint4*>(&ob[8]);
    } else if (MODE == 2) {
        float xv[16];
#pragma unroll
        for (int q = 0; q < 4; ++q)
            *reinterpret_cast<float4*>(&xv[q * 4]) =
                *reinterpret_cast<const float4*>(&auxX[idx + q * 4]);
        __hip_bfloat16 ob[16];
#pragma unroll
        for (int e = 0; e < 16; ++e) ob[e] = f2bf(cv[e] + xv[e]);
        *reinterpret_cast<uint4*>(&outB[idx])     = *reinterpret_cast<const uint4*>(&ob[0]);
        *reinterpret_cast<uint4*>(&outB[idx + 8]) = *reinterpret_cast<const uint4*>(&ob[8]);
    } else if (MODE == 4) {
        unsigned short hs[16], ss[16]; float xv[16], ov[16];
        *reinterpret_cast<uint4*>(&hs[0]) = *reinterpret_cast<const uint4*>(&auxH[idx]);
        *reinterpret_cast<uint4*>(&hs[8]) = *reinterpret_cast<const uint4*>(&auxH[idx + 8]);
        *reinterpret_cast<uint4*>(&ss[0]) = *reinterpret_cast<const uint4*>(&auxS[idx]);
        *reinterpret_cast<uint4*>(&ss[8]) = *reinterpret_cast<const uint4*>(&auxS[idx + 8]);
#pragma unroll
        for (int q = 0; q < 4; ++q)
            *reinterpret_cast<float4*>(&xv[q * 4]) =
                *reinterpret_cast<const float4*>(&auxX[idx + q * 4]);
#pragma unroll
        for (int e = 0; e < 16; ++e)
            ov[e] = bf2f(__hip_bfloat16_raw{hs[e]})
                  + bf2f(__hip_bfloat16_raw{ss[e]}) * cv[e] + xv[e];
#pragma unroll
        for (int q = 0; q < 4; ++q)
            *reinterpret_cast<float4*>(&outF[idx + q * 4]) =
                *reinterpret_cast<const float4*>(&ov[q * 4]);
    } else if (MODE == 5) {
        unsigned short ss[16]; float ov[16];
        *reinterpret_cast<uint4*>(&ss[0]) = *reinterpret_cast<const uint4*>(&auxS[idx]);
        *reinterpret_cast<uint4*>(&ss[8]) = *reinterpret_cast<const uint4*>(&auxS[idx + 8]);
#pragma unroll
        for (int q = 0; q < 4; ++q)
            *reinterpret_cast<float4*>(&ov[q * 4]) =
                *reinterpret_cast<const float4*>(&outF[idx + q * 4]);
#pragma unroll
        for (int e = 0; e < 16; ++e)
            ov[e] += bf2f(__hip_bfloat16_raw{ss[e]}) * cv[e];
#pragma unroll
        for (int q = 0; q < 4; ++q)
            *reinterpret_cast<float4*>(&outF[idx + q * 4]) =
                *reinterpret_cast<const float4*>(&ov[q * 4]);
    } else if (MODE == 6) {
        unsigned short hs[16]; float xv[16], gf[16], ov[16];
        *reinterpret_cast<uint4*>(&hs[0]) = *reinterpret_cast<const uint4*>(&auxH[idx]);
        *reinterpret_cast<uint4*>(&hs[8]) = *reinterpret_cast<const uint4*>(&auxH[idx + 8]);
#pragma unroll
        for (int q = 0; q < 4; ++q) {
            *reinterpret_cast<float4*>(&xv[q * 4]) =
                *reinterpret_cast<const float4*>(&auxX[idx + q * 4]);
            *reinterpret_cast<float4*>(&gf[q * 4]) =
                *reinterpret_cast<const float4*>(&auxG[idx + q * 4]);
        }
#pragma unroll
        for (int e = 0; e < 16; ++e)
            ov[e] = bf2f(__hip_bfloat16_raw{hs[e]}) + gf[e] * cv[e] + xv[e];
#pragma unroll
        for (int q = 0; q < 4; ++q)
            *reinterpret_cast<float4*>(&outF[idx + q * 4]) =
                *reinterpret_cast<const float4*>(&ov[q * 4]);
    } else {  // MODE 7
        float ov[16];
#pragma unroll
        for (int e = 0; e < 16; ++e)
            ov[e] = 1.f / (1.f + __expf(-cv[e]));
#pragma unroll
        for (int q = 0; q < 4; ++q)
            *reinterpret_cast<float4*>(&outF[idx + q * 4]) =
                *reinterpret_cast<const float4*>(&ov[q * 4]);
    }
}

// ===========================================================================
// 256x256 8-phase GEMM v2 — BALANCED per-phase fragment reads (round-6 fix:
// rounds 2-4 front-loaded all 24 ds_reads into phase 1, concentrating the
// LDS-return pipe into one barrier region that cannot overlap the MFMA
// regions -> LDS-burst + MFMA serialized, MfmaUtil 20%. Now each phase reads
// only what its MFMA cluster needs: p1 af[0..3]+b0 (12), p2 af[4..7] (8),
// p3 b1 (4), p4 none — m201's per-phase interleave).
// STG issue slots: p1 j3(t+1), p3 j0(t+2), p4 j1,j2(t+2): every slot's
// overwrite-issue is >= 1 full barrier region after its last read issue,
// plus >=200cy DMA latency. vmcnt(6) boundary math unchanged (6 loads of
// tile t+2 in flight).
// ===========================================================================
#define STG256(tau, j)                                                         \
  do { if ((tau) * 64 < K) {                                                   \
    const int _sb = ((((tau) & 1) * 4) + (j)) * 8192;                          \
    const int _k0 = (tau) * 64;                                                \
    const __hip_bfloat16 *_s0, *_s1;                                           \
    if ((j) < 2) {                                                             \
      _s0 = A + (size_t)(bmr + (j) * 128 + r0) * K + _k0 + colg;               \
      _s1 = A + (size_t)(bmr + (j) * 128 + r1) * K + _k0 + colg;               \
    } else {                                                                   \
      const int _w0 = bnr + ((j) == 2 ? 128 : 0);                              \
      _s0 = W + (size_t)(_w0 + r0) * Wstr + _k0 + colg;                        \
      _s1 = W + (size_t)(_w0 + r1) * Wstr + _k0 + colg;                        \
    }                                                                          \
    GL2LDS(_s0, &lds[_sb + wid * 512]);                                        \
    GL2LDS(_s1, &lds[_sb + 4096 + wid * 512]);                                 \
  } } while (0)

#define LDA_H(buf, mh)                                                         \
  { const int _ab = ((buf) * 4 + wr) * 8192;                                   \
    _Pragma("unroll") for (int mf = 0; mf < 4; ++mf)                           \
    _Pragma("unroll") for (int k2 = 0; k2 < 2; ++k2)                           \
      af[(mh) * 4 + mf][k2] = *reinterpret_cast<const bf16x8*>(                \
        &lds[_ab + (((mh) * 4 + mf) * 16 + l15) * 64                           \
             + (((k2 * 4 + quad) ^ sw7) * 8)]); }

#define LDB_TO(dst, buf, nh)                                                   \
  { const int _bb = ((buf) * 4 + ((wc >> 1) ? 2 : 3)) * 8192;                  \
    _Pragma("unroll") for (int nf = 0; nf < 2; ++nf)                           \
    _Pragma("unroll") for (int k2 = 0; k2 < 2; ++k2)                           \
      dst[nf][k2] = *reinterpret_cast<const bf16x8*>(                          \
        &lds[_bb + ((wc & 1) * 64 + (nh) * 32 + nf * 16 + l15) * 64            \
             + (((k2 * 4 + quad) ^ sw7) * 8)]); }

#define MFQ(MH, NH, BARR)                                                      \
  _Pragma("unroll") for (int mf = 0; mf < 4; ++mf)                             \
  _Pragma("unroll") for (int nf = 0; nf < 2; ++nf)                             \
  _Pragma("unroll") for (int k2 = 0; k2 < 2; ++k2)                             \
    acc[(MH) * 4 + mf][(NH) * 2 + nf] =                                        \
      __builtin_amdgcn_mfma_f32_16x16x32_bf16(af[(MH) * 4 + mf][k2],           \
        BARR[nf][k2], acc[(MH) * 4 + mf][(NH) * 2 + nf], 0, 0, 0);

#define TILE_STEP(tt, buf)                                                     \
  {                                                                            \
    LDA_H(buf, 0); LDB_TO(bfa, buf, 0);                                        \
    STG256((tt) + 1, 3);                                                       \
    BARX();                                                                    \
    __builtin_amdgcn_s_setprio(1); MFQ(0, 0, bfa); __builtin_amdgcn_s_setprio(0);\
    BARX();                                                                    \
    LDA_H(buf, 1);                                                             \
    BARX();                                                                    \
    __builtin_amdgcn_s_setprio(1); MFQ(1, 0, bfa); __builtin_amdgcn_s_setprio(0);\
    BARX();                                                                    \
    LDB_TO(bfb, buf, 1);                                                       \
    STG256((tt) + 2, 0);                                                       \
    BARX();                                                                    \
    __builtin_amdgcn_s_setprio(1); MFQ(0, 1, bfb); __builtin_amdgcn_s_setprio(0);\
    BARX();                                                                    \
    STG256((tt) + 2, 1);                                                       \
    STG256((tt) + 2, 2);                                                       \
    BARX();                                                                    \
    __builtin_amdgcn_s_setprio(1); MFQ(1, 1, bfb); __builtin_amdgcn_s_setprio(0);\
    if ((tt) + 2 == nt) { WAITV0(); } else { WAITV6(); }                       \
    BARX();                                                                    \
  }

struct G256Ctx {
    int bm, bn;
    int tid, lane, wid, wr, wc, l15, quad, sw7, r0, r1, colg;
};

__device__ __forceinline__ void g256_decode(G256Ctx& c, int b, int nbn, int nwg)
{
    const int s = (b & 7) * (nwg >> 3) + (b >> 3);   // bijective (nwg % 8 == 0)
    c.bm = s / nbn; c.bn = s % nbn;
    c.tid = threadIdx.x; c.lane = c.tid & 63; c.wid = c.tid >> 6;
    c.wr = c.wid >> 2; c.wc = c.wid & 3;
    c.l15 = c.lane & 15; c.quad = c.lane >> 4; c.sw7 = c.l15 & 7;
    c.r0 = c.tid >> 3; c.r1 = c.r0 + 64;
    c.colg = ((c.tid & 7) ^ (c.r0 & 7)) * 8;
}

__device__ __forceinline__ void g256_core(
    const __hip_bfloat16* __restrict__ A, const __hip_bfloat16* __restrict__ W,
    int K, int Wstr, const G256Ctx& c, unsigned short* lds, floatx4 acc[8][4])
{
    const int bmr = c.bm * 256, bnr = c.bn * 256;
    const int wid = c.wid, wr = c.wr, wc = c.wc;
    const int l15 = c.l15, quad = c.quad, sw7 = c.sw7;
    const int r0 = c.r0, r1 = c.r1, colg = c.colg;
    const int nt = K >> 6;

    bf16x8 af[8][2], bfa[2][2], bfb[2][2];

    // prologue: halves 0..6 (tile0 j0-3, tile1 j0-2), wait tile0, rendezvous
    STG256(0, 0); STG256(0, 1); STG256(0, 2); STG256(0, 3);
    STG256(1, 0); STG256(1, 1); STG256(1, 2);
    WAITV6();
    BARX();

    for (int t = 0; t < nt; t += 2) {
        TILE_STEP(t, 0);
        TILE_STEP(t + 1, 1);
    }
    WAITV0();
}

template <int MODE>
__global__ __launch_bounds__(512, 2)
void gemm256(const __hip_bfloat16* __restrict__ A, const __hip_bfloat16* __restrict__ W,
             int K, int Wstr, int Nn,
             __hip_bfloat16* __restrict__ outB, float* __restrict__ outF,
             const __hip_bfloat16* __restrict__ auxS, const __hip_bfloat16* __restrict__ auxH,
             const float* __restrict__ auxX, const float* __restrict__ auxG)
{
    __shared__ __align__(16) unsigned short lds[65536];  // 128 KB
    G256Ctx c; g256_decode(c, blockIdx.x, Nn >> 8, gridDim.x);

    floatx4 acc[8][4];
#pragma unroll
    for (int i = 0; i < 8; ++i)
#pragma unroll
        for (int j = 0; j < 4; ++j) acc[i][j] = floatx4{0.f, 0.f, 0.f, 0.f};

    g256_core(A, W, K, Wstr, c, lds, acc);

    float* scr = reinterpret_cast<float*>(lds) + c.wid * 1088;
    const int row_l = c.lane >> 2, cb = (c.lane & 3) * 16;
#pragma unroll
    for (int i = 0; i < 8; ++i) {
        float cv[16];
        xpose_band(acc[i], scr, c.lane, cv);
        const int grow = c.bm * 256 + c.wr * 128 + i * 16 + row_l;
        const int gcol = c.bn * 256 + c.wc * 64 + cb;
        const size_t idx = (size_t)grow * Nn + gcol;
        mode_store<MODE>(cv, idx, outB, outF, auxS, auxH, auxX, auxG);
    }
}

// ---------------------------------------------------------------------------
// 128x128 GEMM core (proven): 4 waves (2x2 of 64x64), BK=64, global_load_lds
// staging with XOR col-group swizzle (0 bank conflicts).
// ---------------------------------------------------------------------------
#define BM 128
#define BN 128
#define BKK 64

__device__ __forceinline__ void gemm_core(
    const __hip_bfloat16* __restrict__ A, const __hip_bfloat16* __restrict__ W,
    int K, int Wstr, int bm, int bn, unsigned short* lds, floatx4 acc[4][4])
{
    const int tid  = threadIdx.x;
    const int lane = tid & 63, wid = tid >> 6;
    const int l15  = lane & 15, quad = lane >> 4;
    const int m0   = (wid & 1) * 64;
    const int n0   = (wid >> 1) * 64;
    const int srow  = lane >> 3;
    const int gcolg = (lane & 7) ^ srow;
    const int s0    = wid * 4;
    const int swzbase = l15 & 7;

    for (int k0 = 0; k0 < K; k0 += BKK) {
#pragma unroll
        for (int t = 0; t < 4; ++t) {
            const int s   = s0 + t;
            const int row = s * 8 + srow;
            GL2LDS(A + (size_t)(bm * BM + row) * K    + k0 + gcolg * 8,
                   &lds[s * 512]);
            GL2LDS(W + (size_t)(bn * BN + row) * Wstr + k0 + gcolg * 8,
                   &lds[8192 + s * 512]);
        }
        __syncthreads();
#pragma unroll
        for (int kk = 0; kk < BKK; kk += 32) {
            const int swz = (((kk >> 3) + quad) ^ swzbase) * 8;
            bf16x8 afr[4], bfr[4];
#pragma unroll
            for (int i = 0; i < 4; ++i)
                afr[i] = *reinterpret_cast<const bf16x8*>(
                    &lds[(m0 + i * 16 + l15) * BKK + swz]);
#pragma unroll
            for (int j = 0; j < 4; ++j)
                bfr[j] = *reinterpret_cast<const bf16x8*>(
                    &lds[8192 + (n0 + j * 16 + l15) * BKK + swz]);
#pragma unroll
            for (int i = 0; i < 4; ++i)
#pragma unroll
                for (int j = 0; j < 4; ++j)
                    acc[i][j] = __builtin_amdgcn_mfma_f32_16x16x32_bf16(
                        afr[i], bfr[j], acc[i][j], 0, 0, 0);
        }
        __syncthreads();
    }
}

template <int MODE>
__global__ __launch_bounds__(256, 2)
void gemm_bt(const __hip_bfloat16* __restrict__ A,
             const __hip_bfloat16* __restrict__ W,
             int K, int Wstr, int Nn,
             __hip_bfloat16* __restrict__ outB,
             float* __restrict__ outF,
             const __hip_bfloat16* __restrict__ auxS,
             const __hip_bfloat16* __restrict__ auxH,
             const float* __restrict__ auxX,
             const float* __restrict__ auxG)
{
    __shared__ __align__(16) unsigned short lds[16384];
    const int bm = blockIdx.x, bn = blockIdx.y;
    const int tid = threadIdx.x, lane = tid & 63, wid = tid >> 6;
    const int m0 = (wid & 1) * 64, n0 = (wid >> 1) * 64;

    floatx4 acc[4][4];
#pragma unroll
    for (int i = 0; i < 4; ++i)
#pragma unroll
        for (int j = 0; j < 4; ++j)
            acc[i][j] = floatx4{0.f, 0.f, 0.f, 0.f};

    gemm_core(A, W, K, Wstr, bm, bn, lds, acc);

    float* scr = reinterpret_cast<float*>(lds) + wid * 1088;
    const int row_l = lane >> 2, cb = (lane & 3) * 16;
#pragma unroll
    for (int i = 0; i < 4; ++i) {
        float cv[16];
        xpose_band(acc[i], scr, lane, cv);
        const int grow = bm * BM + m0 + i * 16 + row_l;
        const int gcol = bn * BN + n0 + cb;
        const size_t idx = (size_t)grow * Nn + gcol;
        mode_store<MODE>(cv, idx, outB, outF, auxS, auxH, auxX, auxG);
    }
}

__global__ __launch_bounds__(256, 2)
void gemm_qkv(const __hip_bfloat16* __restrict__ A0, const __hip_bfloat16* __restrict__ A1,
              const __hip_bfloat16* __restrict__ A2,
              const __hip_bfloat16* __restrict__ W0, const __hip_bfloat16* __restrict__ W1,
              const __hip_bfloat16* __restrict__ W2,
              __hip_bfloat16* __restrict__ O0, __hip_bfloat16* __restrict__ O1,
              __hip_bfloat16* __restrict__ O2)
{
    __shared__ __align__(16) unsigned short lds[16384];
    const int z = blockIdx.z;
    const __hip_bfloat16* A = z == 0 ? A0 : z == 1 ? A1 : A2;
    const __hip_bfloat16* W = z == 0 ? W0 : z == 1 ? W1 : W2;
    __hip_bfloat16*       O = z == 0 ? O0 : z == 1 ? O1 : O2;
    const int bm = blockIdx.x, bn = blockIdx.y;
    const int tid = threadIdx.x, lane = tid & 63, wid = tid >> 6;
    const int m0 = (wid & 1) * 64, n0 = (wid >> 1) * 64;

    floatx4 acc[4][4];
#pragma unroll
    for (int i = 0; i < 4; ++i)
#pragma unroll
        for (int j = 0; j < 4; ++j)
            acc[i][j] = floatx4{0.f, 0.f, 0.f, 0.f};

    gemm_core(A, W, DD, DD, bm, bn, lds, acc);

    float* scr = reinterpret_cast<float*>(lds) + wid * 1088;
    const int row_l = lane >> 2, cb = (lane & 3) * 16;
#pragma unroll
    for (int i = 0; i < 4; ++i) {
        float cv[16];
        xpose_band(acc[i], scr, lane, cv);
        const int grow = bm * BM + m0 + i * 16 + row_l;
        const int gcol = bn * BN + n0 + cb;
        const size_t idx = (size_t)grow * DD + gcol;
        __hip_bfloat16 ob[16];
#pragma unroll
        for (int e = 0; e < 16; ++e) {
            float v = cv[e];
            if (z == 2) v = 1.f / (1.f + __expf(-v));
            ob[e] = f2bf(v);
        }
        *reinterpret_cast<uint4*>(&O[idx])     = *reinterpret_cast<const uint4*>(&ob[0]);
        *reinterpret_cast<uint4*>(&O[idx + 8]) = *reinterpret_cast<const uint4*>(&ob[8]);
    }
}

// ---------------------------------------------------------------------------
// WKV parallel scan over T (chunked two-pass), 4 channels/thread.
// ---------------------------------------------------------------------------
__global__ __launch_bounds__(192)
void wkv_passA(const float* __restrict__ w_log,
               const __hip_bfloat16* __restrict__ k,
               const __hip_bfloat16* __restrict__ v,
               float* __restrict__ SA, float* __restrict__ SB,
               float* __restrict__ SP)
{
    const int c  = threadIdx.x * 4;   // 0..764
    const int j  = blockIdx.x;        // chunk
    const int bb = blockIdx.y;        // batch
    float wl[4];
    load4f(w_log + c, wl);
    const float w4[4] = {-__expf(wl[0]), -__expf(wl[1]), -__expf(wl[2]), -__expf(wl[3])};
    const size_t base = ((size_t)bb * TT + j * CCH) * DD + c;
    float a[4] = {0.f, 0.f, 0.f, 0.f}, b2[4] = {0.f, 0.f, 0.f, 0.f};
    float p[4] = {-1e30f, -1e30f, -1e30f, -1e30f};
#pragma unroll 4
    for (int t = 0; t < CCH; ++t) {
        const size_t o = base + (size_t)t * DD;
        float kt[4], vt[4];
        load4f(k + o, kt);
        load4f(v + o, vt);
#pragma unroll
        for (int e = 0; e < 4; ++e) {
            const float ww2 = p[e] + w4[e];
            const float p2  = fmaxf(ww2, kt[e]);
            const float e1  = __expf(ww2 - p2);
            const float e2  = __expf(kt[e] - p2);
            a[e]  = e1 * a[e]  + e2 * vt[e];
            b2[e] = e1 * b2[e] + e2;
            p[e]  = p2;
        }
    }
    const size_t si = ((size_t)bb * PCH + j) * DD + c;
    *reinterpret_cast<float4*>(&SA[si]) = float4{a[0], a[1], a[2], a[3]};
    *reinterpret_cast<float4*>(&SB[si]) = float4{b2[0], b2[1], b2[2], b2[3]};
    *reinterpret_cast<float4*>(&SP[si]) = float4{p[0], p[1], p[2], p[3]};
}

__global__ __launch_bounds__(256)
void wkv_scanj(const float* __restrict__ w_log,
               float* __restrict__ SA, float* __restrict__ SB,
               float* __restrict__ SP)
{
    const int idx = blockIdx.x * 256 + threadIdx.x;  // 0..B*D/4-1
    const int c = (idx * 4) % DD, bb = (idx * 4) / DD;
    float wl[4];
    load4f(w_log + c, wl);
    float wC[4];
#pragma unroll
    for (int e = 0; e < 4; ++e) wC[e] = -__expf(wl[e]) * (float)CCH;
    float a[4] = {0.f, 0.f, 0.f, 0.f}, b2[4] = {0.f, 0.f, 0.f, 0.f};
    float p[4] = {-1e30f, -1e30f, -1e30f, -1e30f};
#pragma unroll
    for (int j = 0; j < PCH; ++j) {
        const size_t si = ((size_t)bb * PCH + j) * DD + c;
        float aj[4], bj[4], pj[4];
        load4f(SA + si, aj); load4f(SB + si, bj); load4f(SP + si, pj);
        *reinterpret_cast<float4*>(&SA[si]) = float4{a[0], a[1], a[2], a[3]};
        *reinterpret_cast<float4*>(&SB[si]) = float4{b2[0], b2[1], b2[2], b2[3]};
        *reinterpret_cast<float4*>(&SP[si]) = float4{p[0], p[1], p[2], p[3]};
#pragma unroll
        for (int e = 0; e < 4; ++e) {
            const float pd = p[e] + wC[e];
            const float pn = fmaxf(pd, pj[e]);
            const float e1 = __expf(pd - pn);
            const float e2 = __expf(pj[e] - pn);
            a[e]  = e1 * a[e]  + e2 * aj[e];
            b2[e] = e1 * b2[e] + e2 * bj[e];
            p[e]  = pn;
        }
    }
}

__global__ __launch_bounds__(192)
void wkv_passB(const float* __restrict__ w_log, const float* __restrict__ u,
               const __hip_bfloat16* __restrict__ k,
               const __hip_bfloat16* __restrict__ v,
               const __hip_bfloat16* __restrict__ r,
               __hip_bfloat16* __restrict__ rw,
               const float* __restrict__ SA, const float* __restrict__ SB,
               const float* __restrict__ SP)
{
    const int c  = threadIdx.x * 4;
    const int j  = blockIdx.x;
    const int bb = blockIdx.y;
    float wl[4], uu[4];
    load4f(w_log + c, wl);
    load4f(u + c, uu);
    const float w4[4] = {-__expf(wl[0]), -__expf(wl[1]), -__expf(wl[2]), -__expf(wl[3])};
    const size_t si = ((size_t)bb * PCH + j) * DD + c;
    float aa[4], bbv[4], pp[4];
    load4f(SA + si, aa); load4f(SB + si, bbv); load4f(SP + si, pp);
    const size_t base = ((size_t)bb * TT + j * CCH) * DD + c;
#pragma unroll 4
    for (int t = 0; t < CCH; ++t) {
        const size_t o = base + (size_t)t * DD;
        float kt[4], vt[4], rt[4];
        load4f(k + o, kt);
        load4f(v + o, vt);
        load4f(r + o, rt);
        __hip_bfloat16 ob[4];
#pragma unroll
        for (int e = 0; e < 4; ++e) {
            const float ww = uu[e] + kt[e];
            const float pm = fmaxf(pp[e], ww);
            const float e1 = __expf(pp[e] - pm);
            const float e2 = __expf(ww - pm);
            const float ov = __fdividef(e1 * aa[e] + e2 * vt[e], e1 * bbv[e] + e2);
            ob[e] = f2bf(rt[e] * ov);
            const float ww2 = pp[e] + w4[e];
            const float p2  = fmaxf(ww2, kt[e]);
            const float e1b = __expf(ww2 - p2);
            const float e2b = __expf(kt[e] - p2);
            aa[e]  = e1b * aa[e]  + e2b * vt[e];
            bbv[e] = e1b * bbv[e] + e2b;
            pp[e]  = p2;
        }
        *reinterpret_cast<ushort4*>(&rw[o]) = *reinterpret_cast<const ushort4*>(ob);
    }
}

// ---------------------------------------------------------------------------
extern "C" void kernel_launch(void* const* d_in, const int* in_sizes, int n_in,
                              void* d_out, int out_size, void* d_ws, size_t ws_size,
                              hipStream_t stream)
{
    (void)in_sizes; (void)n_in; (void)out_size;
    const float* x     = (const float*)d_in[0];
    const float* ln1_g = (const float*)d_in[3];
    const float* ln1_b = (const float*)d_in[4];
    const float* ln2_g = (const float*)d_in[5];
    const float* ln2_b = (const float*)d_in[6];
    const float* mu_k  = (const float*)d_in[7];
    const float* mu_v  = (const float*)d_in[8];
    const float* mu_r  = (const float*)d_in[9];
    const float* w_log = (const float*)d_in[10];
    const float* u     = (const float*)d_in[11];
    const float* Wk    = (const float*)d_in[12];
    const float* Wv    = (const float*)d_in[13];
    const float* Wr    = (const float*)d_in[14];
    const float* Wo    = (const float*)d_in[15];
    const float* cmu_k = (const float*)d_in[16];
    const float* cmu_r = (const float*)d_in[17];
    const float* Ck    = (const float*)d_in[18];
    const float* Cv    = (const float*)d_in[19];
    const float* Cr    = (const float*)d_in[20];
    float* out = (float*)d_out;

    const size_t ND = (size_t)NROWS * DD;
    const size_t SL = ND * 2;
    const size_t WBYTES = (size_t)(5 * DW + 2 * DH) * 2;
    const size_t NSTATE = (size_t)BBATCH * PCH * DD;
    const size_t TAIL = WBYTES + 2 * (size_t)NROWS * sizeof(float)
                      + 3 * NSTATE * sizeof(float);
    int nslots;
    if      (ws_size >= 7 * SL + TAIL) nslots = 7;
    else if (ws_size >= 6 * SL + TAIL) nslots = 6;
    else if (ws_size >= 5 * SL + TAIL) nslots = 5;
    else return;

    char* w = (char*)d_ws;
    __hip_bfloat16* S0 = (__hip_bfloat16*)(w);
    __hip_bfloat16* S1 = (__hip_bfloat16*)(w + 1 * SL);
    __hip_bfloat16* S2 = (__hip_bfloat16*)(w + 2 * SL);
    __hip_bfloat16* S3 = (__hip_bfloat16*)(w + 3 * SL);
    __hip_bfloat16* S4 = (__hip_bfloat16*)(w + 4 * SL);
    __hip_bfloat16* S5 = (__hip_bfloat16*)(w + 5 * SL);
    __hip_bfloat16* WB  = (__hip_bfloat16*)(w + (size_t)nslots * SL);
    __hip_bfloat16* WkB = WB;
    __hip_bfloat16* WvB = WB + 1ull * DW;
    __hip_bfloat16* WrB = WB + 2ull * DW;
    __hip_bfloat16* WoB = WB + 3ull * DW;
    __hip_bfloat16* CrB = WB + 4ull * DW;
    __hip_bfloat16* CkB = WB + 5ull * DW;
    __hip_bfloat16* CvB = CkB + DH;
    float* meanB = (float*)(w + (size_t)nslots * SL + WBYTES);
    float* rstdB = meanB + NROWS;
    float* SAb = rstdB + NROWS;
    float* SBb = SAb + NSTATE;
    float* SPb = SBb + NSTATE;

    const int LN_GRID  = NROWS / 4;            // 4096
    const int MIX_GRID = (int)(ND / 2048);     // 6144 (8 ch/thread)
    const dim3 g768(NROWS / BM, DD / BN);      // (128, 6)
    const dim3 g1536(NROWS / BM, HHALF / BN);  // (128, 12) fallback FFN halves
    const dim3 gqkv3(NROWS / BM, DD / BN, 3);
    const dim3 gqkv2(NROWS / BM, DD / BN, 2);
    const dim3 gwkv(PCH, BBATCH);              // (16,16), 192 thr (4 ch/thread)
    const int SCANJ_GRID = (BBATCH * DD / 4) / 256;  // 12
    // 256-tile grids (1-D, divisible by 8 for the XCD swizzle)
    const int G256_768 = (NROWS / 256) * (DD / 256);    // 64*3  = 192
    const int G256_HID = (NROWS / 256) * (HIDN / 256);  // 64*12 = 768

    cvt_all<<<7488, 256, 0, stream>>>(Wk, Wv, Wr, Wo, Cr, Ck, Cv, WB);

    ln_stats_k<float><<<LN_GRID, 256, 0, stream>>>(x, meanB, rstdB);
    mix_k<float, 3><<<MIX_GRID, 256, 0, stream>>>(x, meanB, rstdB, ln1_g, ln1_b,
                                                  mu_k, mu_v, mu_r, S0, S1, S2);

    if (nslots == 7) {
        gemm_qkv<<<gqkv3, 256, 0, stream>>>(S0, S1, S2, WkB, WvB, WrB, S3, S4, S5);
        wkv_passA<<<gwkv, 192, 0, stream>>>(w_log, S3, S4, SAb, SBb, SPb);
        wkv_scanj<<<SCANJ_GRID, 256, 0, stream>>>(w_log, SAb, SBb, SPb);
        wkv_passB<<<gwkv, 192, 0, stream>>>(w_log, u, S3, S4, S5, S1, SAb, SBb, SPb); // rw->S1
        gemm_bt<2><<<g768, 256, 0, stream>>>(S1, WoB, DD, DD, DD, S2, nullptr,
                                             nullptr, nullptr, x, nullptr);  // h->S2
        ln_stats_k<__hip_bfloat16><<<LN_GRID, 256, 0, stream>>>(S2, meanB, rstdB);
        mix_k<__hip_bfloat16, 2><<<MIX_GRID, 256, 0, stream>>>(S2, meanB, rstdB, ln2_g, ln2_b,
                                                               cmu_k, nullptr, cmu_r,
                                                               S0, nullptr, S3);
        gemm_bt<1><<<g768, 256, 0, stream>>>(S3, CrB, DD, DD, DD, S1, nullptr,
                                             nullptr, nullptr, nullptr, nullptr); // gate->S1
        // merged FFN on the balanced 8-phase core: kk in contiguous S3..S6
        gemm256<3><<<G256_HID, 512, 0, stream>>>(S0, CkB, DD, DD, HIDN,
                                                 S3, nullptr, nullptr, nullptr, nullptr, nullptr);
        gemm256<4><<<G256_768, 512, 0, stream>>>(S3, CvB, HIDN, HIDN, DD,
                                                 nullptr, out, S1, S2, x, nullptr);
    } else if (nslots == 6) {
        gemm_qkv<<<gqkv3, 256, 0, stream>>>(S0, S1, S2, WkB, WvB, WrB, S3, S4, S5);
        wkv_passA<<<gwkv, 192, 0, stream>>>(w_log, S3, S4, SAb, SBb, SPb);
        wkv_scanj<<<SCANJ_GRID, 256, 0, stream>>>(w_log, SAb, SBb, SPb);
        wkv_passB<<<gwkv, 192, 0, stream>>>(w_log, u, S3, S4, S5, S0, SAb, SBb, SPb); // rw->S0
        gemm_bt<2><<<g768, 256, 0, stream>>>(S0, WoB, DD, DD, DD, S1, nullptr,
                                             nullptr, nullptr, x, nullptr);  // h->S1
        ln_stats_k<__hip_bfloat16><<<LN_GRID, 256, 0, stream>>>(S1, meanB, rstdB);
        mix_k<__hip_bfloat16, 2><<<MIX_GRID, 256, 0, stream>>>(S1, meanB, rstdB, ln2_g, ln2_b,
                                                               cmu_k, nullptr, cmu_r,
                                                               S0, nullptr, S2);
        // gate as fp32 parked in d_out (each MODE-6 block reads only its own tile)
        gemm_bt<7><<<g768, 256, 0, stream>>>(S2, CrB, DD, DD, DD, nullptr, out,
                                             nullptr, nullptr, nullptr, nullptr);
        gemm256<3><<<G256_HID, 512, 0, stream>>>(S0, CkB, DD, DD, HIDN,
                                                 S2, nullptr, nullptr, nullptr, nullptr, nullptr);
        gemm256<6><<<G256_768, 512, 0, stream>>>(S2, CvB, HIDN, HIDN, DD,
                                                 nullptr, out, nullptr, S1, x, out);
    } else {
        // 5-slot fallback: legacy verified schedule
        gemm_qkv<<<gqkv2, 256, 0, stream>>>(S0, S1, nullptr, WkB, WvB, nullptr,
                                            S3, S4, nullptr);       // k->S3, v->S4
        gemm_bt<1><<<g768, 256, 0, stream>>>(S2, WrB, DD, DD, DD, S0, nullptr,
                                             nullptr, nullptr, nullptr, nullptr); // r->S0
        wkv_passA<<<gwkv, 192, 0, stream>>>(w_log, S3, S4, SAb, SBb, SPb);
        wkv_scanj<<<SCANJ_GRID, 256, 0, stream>>>(w_log, SAb, SBb, SPb);
        wkv_passB<<<gwkv, 192, 0, stream>>>(w_log, u, S3, S4, S0, S1, SAb, SBb, SPb); // rw->S1
        gemm_bt<2><<<g768, 256, 0, stream>>>(S1, WoB, DD, DD, DD, S2, nullptr,
                                             nullptr, nullptr, x, nullptr);       // h->S2
        ln_stats_k<__hip_bfloat16><<<LN_GRID, 256, 0, stream>>>(S2, meanB, rstdB);
        mix_k<__hip_bfloat16, 2><<<MIX_GRID, 256, 0, stream>>>(S2, meanB, rstdB, ln2_g, ln2_b,
                                                               cmu_k, nullptr, cmu_r,
                                                               S0, nullptr, S3);
        gemm_bt<1><<<g768, 256, 0, stream>>>(S3, CrB, DD, DD, DD, S1, nullptr,
                                             nullptr, nullptr, nullptr, nullptr); // cr->S1
        __hip_bfloat16* kk = S3;  // FFN in two 1536-wide halves (kk in S3+S4)
        gemm_bt<3><<<g1536, 256, 0, stream>>>(S0, CkB, DD, DD, HHALF,
                                              kk, nullptr, nullptr, nullptr, nullptr, nullptr);
        gemm_bt<4><<<g768, 256, 0, stream>>>(kk, CvB, HHALF, HIDN, DD,
                                             nullptr, out, S1, S2, x, nullptr);
        gemm_bt<3><<<g1536, 256, 0, stream>>>(S0, CkB + (size_t)HHALF * DD, DD, DD, HHALF,
                                              kk, nullptr, nullptr, nullptr, nullptr, nullptr);
        gemm_bt<5><<<g768, 256, 0, stream>>>(kk, CvB + HHALF, HHALF, HIDN, DD,
                                             nullptr, out, S1, nullptr, nullptr, nullptr);
    }
}

// Round 7
// 580.537 us; speedup vs baseline: 1.0809x; 1.0809x over previous
//
#include <hip/hip_runtime.h>
#include <hip/hip_bf16.h>

// Problem constants (fixed by the reference)
#define DD   768
#define TT   1024
#define BBATCH 16
#define NROWS (BBATCH * TT)   // 16384
#define HIDN 3072
#define HHALF 1536
#define HH 32
#define WW 32
#define DW  (DD * DD)         // 589824
#define DH  (DD * HIDN)       // 2359296
#define CCH 64                // wkv chunk length
#define PCH (TT / CCH)        // 16 chunks

typedef float  floatx4 __attribute__((ext_vector_type(4)));
typedef __bf16 bf16x8  __attribute__((ext_vector_type(8)));

__device__ __forceinline__ float bf2f(__hip_bfloat16 v) { return __bfloat162float(v); }
__device__ __forceinline__ __hip_bfloat16 f2bf(float v) { return __float2bfloat16(v); }
__device__ __forceinline__ float toF(__hip_bfloat16 v) { return __bfloat162float(v); }
__device__ __forceinline__ float toF(float v) { return v; }

__device__ __forceinline__ void load4f(const float* __restrict__ p, float o[4]) {
    const float4 v = *reinterpret_cast<const float4*>(p);
    o[0] = v.x; o[1] = v.y; o[2] = v.z; o[3] = v.w;
}
__device__ __forceinline__ void load4f(const __hip_bfloat16* __restrict__ p, float o[4]) {
    const ushort4 v = *reinterpret_cast<const ushort4*>(p);
    o[0] = bf2f(__hip_bfloat16_raw{v.x});
    o[1] = bf2f(__hip_bfloat16_raw{v.y});
    o[2] = bf2f(__hip_bfloat16_raw{v.z});
    o[3] = bf2f(__hip_bfloat16_raw{v.w});
}
__device__ __forceinline__ void load8f(const float* __restrict__ p, float o[8]) {
    load4f(p, o); load4f(p + 4, o + 4);
}
__device__ __forceinline__ void load8f(const __hip_bfloat16* __restrict__ p, float o[8]) {
    const uint4 v = *reinterpret_cast<const uint4*>(p);
    const unsigned short* s = reinterpret_cast<const unsigned short*>(&v);
#pragma unroll
    for (int e = 0; e < 8; ++e) o[e] = bf2f(__hip_bfloat16_raw{s[e]});
}

// global -> LDS direct DMA, 16 B per lane, dest = uniform base + lane*16
#define GL2LDS(gp, lp)  __builtin_amdgcn_global_load_lds(                     \
    (const __attribute__((address_space(1))) void*)(gp),                      \
    (__attribute__((address_space(3))) void*)(lp), 16, 0, 0)

// ---------------------------------------------------------------------------
// fp32 -> bf16 conversion of ALL weights in one dispatch (7 segments).
// ---------------------------------------------------------------------------
__global__ __launch_bounds__(256)
void cvt_all(const float* __restrict__ w0, const float* __restrict__ w1,
             const float* __restrict__ w2, const float* __restrict__ w3,
             const float* __restrict__ w4, const float* __restrict__ w5,
             const float* __restrict__ w6, __hip_bfloat16* __restrict__ dst)
{
    const int b = blockIdx.x;
    const float* s; size_t dofs; int rel;
    if (b < 2880) {            // 5 x 576 blocks of DW
        const int seg = b / 576; rel = b - seg * 576;
        s = seg == 0 ? w0 : seg == 1 ? w1 : seg == 2 ? w2 : seg == 3 ? w3 : w4;
        dofs = (size_t)seg * DW;
    } else if (b < 5184) {     // Ck
        rel = b - 2880; s = w5; dofs = 5ull * DW;
    } else {                   // Cv
        rel = b - 5184; s = w6; dofs = 5ull * DW + DH;
    }
    const int i = rel * 1024 + threadIdx.x * 4;
    const float4 v = *reinterpret_cast<const float4*>(s + i);
    __hip_bfloat16 o[4] = {f2bf(v.x), f2bf(v.y), f2bf(v.z), f2bf(v.w)};
    *reinterpret_cast<ushort4*>(&dst[dofs + i]) = *reinterpret_cast<const ushort4*>(o);
}

// ---------------------------------------------------------------------------
// Per-row LN stats: one wave per row, vectorized.
// ---------------------------------------------------------------------------
template <typename TIN>
__global__ __launch_bounds__(256)
void ln_stats_k(const TIN* __restrict__ x,
                float* __restrict__ mean, float* __restrict__ rstd)
{
    const int row  = blockIdx.x * 4 + (threadIdx.x >> 6);
    const int lane = threadIdx.x & 63;
    const TIN* xr = x + (size_t)row * DD;
    float s1 = 0.f, s2 = 0.f;
#pragma unroll
    for (int q = 0; q < 3; ++q) {
        float v4[4];
        load4f(xr + 4 * lane + 256 * q, v4);
#pragma unroll
        for (int e = 0; e < 4; ++e) { s1 += v4[e]; s2 += v4[e] * v4[e]; }
    }
#pragma unroll
    for (int off = 32; off > 0; off >>= 1) {
        s1 += __shfl_down(s1, off);
        s2 += __shfl_down(s2, off);
    }
    if (lane == 0) {
        const float m = s1 * (1.f / DD);
        mean[row] = m;
        rstd[row] = rsqrtf(s2 * (1.f / DD) - m * m + 1e-5f);
    }
}

// ---------------------------------------------------------------------------
// LN-on-the-fly + q_shift + token-mix, 8 channels/thread (uint4 bf16 stores).
// ---------------------------------------------------------------------------
template <typename TIN, int NOUT>
__global__ __launch_bounds__(256)
void mix_k(const TIN* __restrict__ x,
           const float* __restrict__ mean, const float* __restrict__ rstd,
           const float* __restrict__ g, const float* __restrict__ b,
           const float* __restrict__ muk,
           const float* __restrict__ muv,
           const float* __restrict__ mur,
           __hip_bfloat16* __restrict__ xk,
           __hip_bfloat16* __restrict__ xv,
           __hip_bfloat16* __restrict__ xr)
{
    const size_t i8 = ((size_t)blockIdx.x * 256 + threadIdx.x) * 8;
    const int c  = (int)(i8 % DD);
    const int n  = (int)((i8 / DD) % TT);
    const int bb = (int)(i8 / ((size_t)DD * TT));
    const int y = n >> 5, xp = n & 31;
    const int grow = bb * TT + n;

    const int grp = c / (DD / 4);
    int ny = y, nx = xp; bool ok;
    if      (grp == 0) { nx = xp - 1; ok = xp > 0;      }
    else if (grp == 1) { nx = xp + 1; ok = xp < WW - 1; }
    else if (grp == 2) { ny = y - 1;  ok = y > 0;       }
    else               { ny = y + 1;  ok = y < HH - 1;  }

    float gg[8], bbv[8];
    load8f(g + c, gg); load8f(b + c, bbv);

    float xc[8];
    load8f(x + (size_t)grow * DD + c, xc);
    const float m = mean[grow], rs = rstd[grow];
    float av[8], sx[8] = {0.f, 0.f, 0.f, 0.f, 0.f, 0.f, 0.f, 0.f};
#pragma unroll
    for (int e = 0; e < 8; ++e) av[e] = (xc[e] - m) * rs * gg[e] + bbv[e];

    if (ok) {
        const int nrow = bb * TT + ny * WW + nx;
        float xn[8];
        load8f(x + (size_t)nrow * DD + c, xn);
        const float m2 = mean[nrow], rs2 = rstd[nrow];
#pragma unroll
        for (int e = 0; e < 8; ++e) sx[e] = (xn[e] - m2) * rs2 * gg[e] + bbv[e];
    }

    float mk[8], mr[8];
    load8f(muk + c, mk); load8f(mur + c, mr);
    __hip_bfloat16 ok8[8], or8[8];
#pragma unroll
    for (int e = 0; e < 8; ++e) {
        ok8[e] = f2bf(av[e] * mk[e] + sx[e] * (1.f - mk[e]));
        or8[e] = f2bf(av[e] * mr[e] + sx[e] * (1.f - mr[e]));
    }
    *reinterpret_cast<uint4*>(&xk[i8]) = *reinterpret_cast<const uint4*>(ok8);
    *reinterpret_cast<uint4*>(&xr[i8]) = *reinterpret_cast<const uint4*>(or8);
    if (NOUT == 3) {
        float mv[8];
        load8f(muv + c, mv);
        __hip_bfloat16 ov8[8];
#pragma unroll
        for (int e = 0; e < 8; ++e)
            ov8[e] = f2bf(av[e] * mv[e] + sx[e] * (1.f - mv[e]));
        *reinterpret_cast<uint4*>(&xv[i8]) = *reinterpret_cast<const uint4*>(ov8);
    }
}

// ---------------------------------------------------------------------------
// Shared epilogue transpose + MODE stores
// ---------------------------------------------------------------------------
__device__ __forceinline__ void xpose_band(const floatx4 accRow[4], float* scr,
                                           int lane, float cv[16])
{
    const int l15 = lane & 15, quad = lane >> 4;
#pragma unroll
    for (int j = 0; j < 4; ++j)
#pragma unroll
        for (int r = 0; r < 4; ++r)
            scr[(quad * 4 + r) * 68 + j * 16 + l15] = accRow[j][r];
    const int row_l = lane >> 2, cb = (lane & 3) * 16;
#pragma unroll
    for (int q = 0; q < 4; ++q)
        *reinterpret_cast<float4*>(&cv[q * 4]) =
            *reinterpret_cast<const float4*>(&scr[row_l * 68 + cb + q * 4]);
}

// MODE: 1=bf16(sigmoid), 2=bf16(acc + xf32), 3=bf16(relu^2),
//       4=f32 out = h + s*acc + x   (s bf16)
//       5=f32 out += s*acc
//       6=f32 out = h + gf*acc + x  (gf fp32; may alias out — own tile only)
//       7=f32 out = sigmoid(acc)
template <int MODE>
__device__ __forceinline__ void mode_store(
    const float cv[16], size_t idx,
    __hip_bfloat16* __restrict__ outB, float* __restrict__ outF,
    const __hip_bfloat16* __restrict__ auxS, const __hip_bfloat16* __restrict__ auxH,
    const float* __restrict__ auxX, const float* __restrict__ auxG)
{
    if (MODE == 1 || MODE == 3) {
        __hip_bfloat16 ob[16];
#pragma unroll
        for (int e = 0; e < 16; ++e) {
            float v = cv[e];
            if (MODE == 1) v = 1.f / (1.f + __expf(-v));
            else { v = fmaxf(v, 0.f); v = v * v; }
            ob[e] = f2bf(v);
        }
        *reinterpret_cast<uint4*>(&outB[idx])     = *reinterpret_cast<const uint4*>(&ob[0]);
        *reinterpret_cast<uint4*>(&outB[idx + 8]) = *reinterpret_cast<const uint4*>(&ob[8]);
    } else if (MODE == 2) {
        float xv[16];
#pragma unroll
        for (int q = 0; q < 4; ++q)
            *reinterpret_cast<float4*>(&xv[q * 4]) =
                *reinterpret_cast<const float4*>(&auxX[idx + q * 4]);
        __hip_bfloat16 ob[16];
#pragma unroll
        for (int e = 0; e < 16; ++e) ob[e] = f2bf(cv[e] + xv[e]);
        *reinterpret_cast<uint4*>(&outB[idx])     = *reinterpret_cast<const uint4*>(&ob[0]);
        *reinterpret_cast<uint4*>(&outB[idx + 8]) = *reinterpret_cast<const uint4*>(&ob[8]);
    } else if (MODE == 4) {
        unsigned short hs[16], ss[16]; float xv[16], ov[16];
        *reinterpret_cast<uint4*>(&hs[0]) = *reinterpret_cast<const uint4*>(&auxH[idx]);
        *reinterpret_cast<uint4*>(&hs[8]) = *reinterpret_cast<const uint4*>(&auxH[idx + 8]);
        *reinterpret_cast<uint4*>(&ss[0]) = *reinterpret_cast<const uint4*>(&auxS[idx]);
        *reinterpret_cast<uint4*>(&ss[8]) = *reinterpret_cast<const uint4*>(&auxS[idx + 8]);
#pragma unroll
        for (int q = 0; q < 4; ++q)
            *reinterpret_cast<float4*>(&xv[q * 4]) =
                *reinterpret_cast<const float4*>(&auxX[idx + q * 4]);
#pragma unroll
        for (int e = 0; e < 16; ++e)
            ov[e] = bf2f(__hip_bfloat16_raw{hs[e]})
                  + bf2f(__hip_bfloat16_raw{ss[e]}) * cv[e] + xv[e];
#pragma unroll
        for (int q = 0; q < 4; ++q)
            *reinterpret_cast<float4*>(&outF[idx + q * 4]) =
                *reinterpret_cast<const float4*>(&ov[q * 4]);
    } else if (MODE == 5) {
        unsigned short ss[16]; float ov[16];
        *reinterpret_cast<uint4*>(&ss[0]) = *reinterpret_cast<const uint4*>(&auxS[idx]);
        *reinterpret_cast<uint4*>(&ss[8]) = *reinterpret_cast<const uint4*>(&auxS[idx + 8]);
#pragma unroll
        for (int q = 0; q < 4; ++q)
            *reinterpret_cast<float4*>(&ov[q * 4]) =
                *reinterpret_cast<const float4*>(&outF[idx + q * 4]);
#pragma unroll
        for (int e = 0; e < 16; ++e)
            ov[e] += bf2f(__hip_bfloat16_raw{ss[e]}) * cv[e];
#pragma unroll
        for (int q = 0; q < 4; ++q)
            *reinterpret_cast<float4*>(&outF[idx + q * 4]) =
                *reinterpret_cast<const float4*>(&ov[q * 4]);
    } else if (MODE == 6) {
        unsigned short hs[16]; float xv[16], gf[16], ov[16];
        *reinterpret_cast<uint4*>(&hs[0]) = *reinterpret_cast<const uint4*>(&auxH[idx]);
        *reinterpret_cast<uint4*>(&hs[8]) = *reinterpret_cast<const uint4*>(&auxH[idx + 8]);
#pragma unroll
        for (int q = 0; q < 4; ++q) {
            *reinterpret_cast<float4*>(&xv[q * 4]) =
                *reinterpret_cast<const float4*>(&auxX[idx + q * 4]);
            *reinterpret_cast<float4*>(&gf[q * 4]) =
                *reinterpret_cast<const float4*>(&auxG[idx + q * 4]);
        }
#pragma unroll
        for (int e = 0; e < 16; ++e)
            ov[e] = bf2f(__hip_bfloat16_raw{hs[e]}) + gf[e] * cv[e] + xv[e];
#pragma unroll
        for (int q = 0; q < 4; ++q)
            *reinterpret_cast<float4*>(&outF[idx + q * 4]) =
                *reinterpret_cast<const float4*>(&ov[q * 4]);
    } else {  // MODE 7
        float ov[16];
#pragma unroll
        for (int e = 0; e < 16; ++e)
            ov[e] = 1.f / (1.f + __expf(-cv[e]));
#pragma unroll
        for (int q = 0; q < 4; ++q)
            *reinterpret_cast<float4*>(&outF[idx + q * 4]) =
                *reinterpret_cast<const float4*>(&ov[q * 4]);
    }
}

// ---------------------------------------------------------------------------
// 128x128 GEMM core (proven): 4 waves (2x2 of 64x64), BK=64, global_load_lds
// staging with XOR col-group swizzle (0 bank conflicts).
// ---------------------------------------------------------------------------
#define BM 128
#define BN 128
#define BKK 64

__device__ __forceinline__ void gemm_core(
    const __hip_bfloat16* __restrict__ A, const __hip_bfloat16* __restrict__ W,
    int K, int Wstr, int bm, int bn, unsigned short* lds, floatx4 acc[4][4])
{
    const int tid  = threadIdx.x;
    const int lane = tid & 63, wid = tid >> 6;
    const int l15  = lane & 15, quad = lane >> 4;
    const int m0   = (wid & 1) * 64;
    const int n0   = (wid >> 1) * 64;
    const int srow  = lane >> 3;
    const int gcolg = (lane & 7) ^ srow;
    const int s0    = wid * 4;
    const int swzbase = l15 & 7;

    for (int k0 = 0; k0 < K; k0 += BKK) {
#pragma unroll
        for (int t = 0; t < 4; ++t) {
            const int s   = s0 + t;
            const int row = s * 8 + srow;
            GL2LDS(A + (size_t)(bm * BM + row) * K    + k0 + gcolg * 8,
                   &lds[s * 512]);
            GL2LDS(W + (size_t)(bn * BN + row) * Wstr + k0 + gcolg * 8,
                   &lds[8192 + s * 512]);
        }
        __syncthreads();
#pragma unroll
        for (int kk = 0; kk < BKK; kk += 32) {
            const int swz = (((kk >> 3) + quad) ^ swzbase) * 8;
            bf16x8 afr[4], bfr[4];
#pragma unroll
            for (int i = 0; i < 4; ++i)
                afr[i] = *reinterpret_cast<const bf16x8*>(
                    &lds[(m0 + i * 16 + l15) * BKK + swz]);
#pragma unroll
            for (int j = 0; j < 4; ++j)
                bfr[j] = *reinterpret_cast<const bf16x8*>(
                    &lds[8192 + (n0 + j * 16 + l15) * BKK + swz]);
#pragma unroll
            for (int i = 0; i < 4; ++i)
#pragma unroll
                for (int j = 0; j < 4; ++j)
                    acc[i][j] = __builtin_amdgcn_mfma_f32_16x16x32_bf16(
                        afr[i], bfr[j], acc[i][j], 0, 0, 0);
        }
        __syncthreads();
    }
}

template <int MODE>
__global__ __launch_bounds__(256, 2)
void gemm_bt(const __hip_bfloat16* __restrict__ A,
             const __hip_bfloat16* __restrict__ W,
             int K, int Wstr, int Nn,
             __hip_bfloat16* __restrict__ outB,
             float* __restrict__ outF,
             const __hip_bfloat16* __restrict__ auxS,
             const __hip_bfloat16* __restrict__ auxH,
             const float* __restrict__ auxX,
             const float* __restrict__ auxG)
{
    __shared__ __align__(16) unsigned short lds[16384];
    const int bm = blockIdx.x, bn = blockIdx.y;
    const int tid = threadIdx.x, lane = tid & 63, wid = tid >> 6;
    const int m0 = (wid & 1) * 64, n0 = (wid >> 1) * 64;

    floatx4 acc[4][4];
#pragma unroll
    for (int i = 0; i < 4; ++i)
#pragma unroll
        for (int j = 0; j < 4; ++j)
            acc[i][j] = floatx4{0.f, 0.f, 0.f, 0.f};

    gemm_core(A, W, K, Wstr, bm, bn, lds, acc);

    float* scr = reinterpret_cast<float*>(lds) + wid * 1088;
    const int row_l = lane >> 2, cb = (lane & 3) * 16;
#pragma unroll
    for (int i = 0; i < 4; ++i) {
        float cv[16];
        xpose_band(acc[i], scr, lane, cv);
        const int grow = bm * BM + m0 + i * 16 + row_l;
        const int gcol = bn * BN + n0 + cb;
        const size_t idx = (size_t)grow * Nn + gcol;
        mode_store<MODE>(cv, idx, outB, outF, auxS, auxH, auxX, auxG);
    }
}

// Batched QKV: z=0 k, z=1 v, z=2 r=sigmoid
__global__ __launch_bounds__(256, 2)
void gemm_qkv(const __hip_bfloat16* __restrict__ A0, const __hip_bfloat16* __restrict__ A1,
              const __hip_bfloat16* __restrict__ A2,
              const __hip_bfloat16* __restrict__ W0, const __hip_bfloat16* __restrict__ W1,
              const __hip_bfloat16* __restrict__ W2,
              __hip_bfloat16* __restrict__ O0, __hip_bfloat16* __restrict__ O1,
              __hip_bfloat16* __restrict__ O2)
{
    __shared__ __align__(16) unsigned short lds[16384];
    const int z = blockIdx.z;
    const __hip_bfloat16* A = z == 0 ? A0 : z == 1 ? A1 : A2;
    const __hip_bfloat16* W = z == 0 ? W0 : z == 1 ? W1 : W2;
    __hip_bfloat16*       O = z == 0 ? O0 : z == 1 ? O1 : O2;
    const int bm = blockIdx.x, bn = blockIdx.y;
    const int tid = threadIdx.x, lane = tid & 63, wid = tid >> 6;
    const int m0 = (wid & 1) * 64, n0 = (wid >> 1) * 64;

    floatx4 acc[4][4];
#pragma unroll
    for (int i = 0; i < 4; ++i)
#pragma unroll
        for (int j = 0; j < 4; ++j)
            acc[i][j] = floatx4{0.f, 0.f, 0.f, 0.f};

    gemm_core(A, W, DD, DD, bm, bn, lds, acc);

    float* scr = reinterpret_cast<float*>(lds) + wid * 1088;
    const int row_l = lane >> 2, cb = (lane & 3) * 16;
#pragma unroll
    for (int i = 0; i < 4; ++i) {
        float cv[16];
        xpose_band(acc[i], scr, lane, cv);
        const int grow = bm * BM + m0 + i * 16 + row_l;
        const int gcol = bn * BN + n0 + cb;
        const size_t idx = (size_t)grow * DD + gcol;
        __hip_bfloat16 ob[16];
#pragma unroll
        for (int e = 0; e < 16; ++e) {
            float v = cv[e];
            if (z == 2) v = 1.f / (1.f + __expf(-v));
            ob[e] = f2bf(v);
        }
        *reinterpret_cast<uint4*>(&O[idx])     = *reinterpret_cast<const uint4*>(&ob[0]);
        *reinterpret_cast<uint4*>(&O[idx + 8]) = *reinterpret_cast<const uint4*>(&ob[8]);
    }
}

// Batched channel-mix front: bn<24 -> Ck (relu^2 -> kk bf16, N=3072);
// bn>=24 -> Cr (sigmoid -> gate fp32 in d_out, N=768). Cr's 768 blocks fill
// the Ck dispatch tail; kk lives in S3..S6, gate in d_out (read back by the
// MODE-6 Cv epilogue, own-tile only).
__global__ __launch_bounds__(256, 2)
void gemm_crck(const __hip_bfloat16* __restrict__ Ak, const __hip_bfloat16* __restrict__ Wk_,
               __hip_bfloat16* __restrict__ kkO,
               const __hip_bfloat16* __restrict__ Ar, const __hip_bfloat16* __restrict__ Wr_,
               float* __restrict__ gateO)
{
    __shared__ __align__(16) unsigned short lds[16384];
    const int bm = blockIdx.x, bny = blockIdx.y;
    const bool isCk = bny < (HIDN / BN);
    const __hip_bfloat16* A = isCk ? Ak : Ar;
    const __hip_bfloat16* W = isCk ? Wk_ : Wr_;
    const int bn = isCk ? bny : bny - (HIDN / BN);
    const int Nn = isCk ? HIDN : DD;
    const int tid = threadIdx.x, lane = tid & 63, wid = tid >> 6;
    const int m0 = (wid & 1) * 64, n0 = (wid >> 1) * 64;

    floatx4 acc[4][4];
#pragma unroll
    for (int i = 0; i < 4; ++i)
#pragma unroll
        for (int j = 0; j < 4; ++j)
            acc[i][j] = floatx4{0.f, 0.f, 0.f, 0.f};

    gemm_core(A, W, DD, DD, bm, bn, lds, acc);

    float* scr = reinterpret_cast<float*>(lds) + wid * 1088;
    const int row_l = lane >> 2, cb = (lane & 3) * 16;
#pragma unroll
    for (int i = 0; i < 4; ++i) {
        float cv[16];
        xpose_band(acc[i], scr, lane, cv);
        const int grow = bm * BM + m0 + i * 16 + row_l;
        const int gcol = bn * BN + n0 + cb;
        const size_t idx = (size_t)grow * Nn + gcol;
        if (isCk) {
            __hip_bfloat16 ob[16];
#pragma unroll
            for (int e = 0; e < 16; ++e) {
                float v = fmaxf(cv[e], 0.f);
                ob[e] = f2bf(v * v);
            }
            *reinterpret_cast<uint4*>(&kkO[idx])     = *reinterpret_cast<const uint4*>(&ob[0]);
            *reinterpret_cast<uint4*>(&kkO[idx + 8]) = *reinterpret_cast<const uint4*>(&ob[8]);
        } else {
            float ov[16];
#pragma unroll
            for (int e = 0; e < 16; ++e)
                ov[e] = 1.f / (1.f + __expf(-cv[e]));
#pragma unroll
            for (int q = 0; q < 4; ++q)
                *reinterpret_cast<float4*>(&gateO[idx + q * 4]) =
                    *reinterpret_cast<const float4*>(&ov[q * 4]);
        }
    }
}

// ---------------------------------------------------------------------------
// WKV parallel scan over T (chunked two-pass), 4 channels/thread.
// ---------------------------------------------------------------------------
__global__ __launch_bounds__(192)
void wkv_passA(const float* __restrict__ w_log,
               const __hip_bfloat16* __restrict__ k,
               const __hip_bfloat16* __restrict__ v,
               float* __restrict__ SA, float* __restrict__ SB,
               float* __restrict__ SP)
{
    const int c  = threadIdx.x * 4;   // 0..764
    const int j  = blockIdx.x;        // chunk
    const int bb = blockIdx.y;        // batch
    float wl[4];
    load4f(w_log + c, wl);
    const float w4[4] = {-__expf(wl[0]), -__expf(wl[1]), -__expf(wl[2]), -__expf(wl[3])};
    const size_t base = ((size_t)bb * TT + j * CCH) * DD + c;
    float a[4] = {0.f, 0.f, 0.f, 0.f}, b2[4] = {0.f, 0.f, 0.f, 0.f};
    float p[4] = {-1e30f, -1e30f, -1e30f, -1e30f};
#pragma unroll 4
    for (int t = 0; t < CCH; ++t) {
        const size_t o = base + (size_t)t * DD;
        float kt[4], vt[4];
        load4f(k + o, kt);
        load4f(v + o, vt);
#pragma unroll
        for (int e = 0; e < 4; ++e) {
            const float ww2 = p[e] + w4[e];
            const float p2  = fmaxf(ww2, kt[e]);
            const float e1  = __expf(ww2 - p2);
            const float e2  = __expf(kt[e] - p2);
            a[e]  = e1 * a[e]  + e2 * vt[e];
            b2[e] = e1 * b2[e] + e2;
            p[e]  = p2;
        }
    }
    const size_t si = ((size_t)bb * PCH + j) * DD + c;
    *reinterpret_cast<float4*>(&SA[si]) = float4{a[0], a[1], a[2], a[3]};
    *reinterpret_cast<float4*>(&SB[si]) = float4{b2[0], b2[1], b2[2], b2[3]};
    *reinterpret_cast<float4*>(&SP[si]) = float4{p[0], p[1], p[2], p[3]};
}

__global__ __launch_bounds__(256)
void wkv_scanj(const float* __restrict__ w_log,
               float* __restrict__ SA, float* __restrict__ SB,
               float* __restrict__ SP)
{
    const int idx = blockIdx.x * 256 + threadIdx.x;  // 0..B*D/4-1
    const int c = (idx * 4) % DD, bb = (idx * 4) / DD;
    float wl[4];
    load4f(w_log + c, wl);
    float wC[4];
#pragma unroll
    for (int e = 0; e < 4; ++e) wC[e] = -__expf(wl[e]) * (float)CCH;
    float a[4] = {0.f, 0.f, 0.f, 0.f}, b2[4] = {0.f, 0.f, 0.f, 0.f};
    float p[4] = {-1e30f, -1e30f, -1e30f, -1e30f};
#pragma unroll
    for (int j = 0; j < PCH; ++j) {
        const size_t si = ((size_t)bb * PCH + j) * DD + c;
        float aj[4], bj[4], pj[4];
        load4f(SA + si, aj); load4f(SB + si, bj); load4f(SP + si, pj);
        *reinterpret_cast<float4*>(&SA[si]) = float4{a[0], a[1], a[2], a[3]};
        *reinterpret_cast<float4*>(&SB[si]) = float4{b2[0], b2[1], b2[2], b2[3]};
        *reinterpret_cast<float4*>(&SP[si]) = float4{p[0], p[1], p[2], p[3]};
#pragma unroll
        for (int e = 0; e < 4; ++e) {
            const float pd = p[e] + wC[e];
            const float pn = fmaxf(pd, pj[e]);
            const float e1 = __expf(pd - pn);
            const float e2 = __expf(pj[e] - pn);
            a[e]  = e1 * a[e]  + e2 * aj[e];
            b2[e] = e1 * b2[e] + e2 * bj[e];
            p[e]  = pn;
        }
    }
}

__global__ __launch_bounds__(192)
void wkv_passB(const float* __restrict__ w_log, const float* __restrict__ u,
               const __hip_bfloat16* __restrict__ k,
               const __hip_bfloat16* __restrict__ v,
               const __hip_bfloat16* __restrict__ r,
               __hip_bfloat16* __restrict__ rw,
               const float* __restrict__ SA, const float* __restrict__ SB,
               const float* __restrict__ SP)
{
    const int c  = threadIdx.x * 4;
    const int j  = blockIdx.x;
    const int bb = blockIdx.y;
    float wl[4], uu[4];
    load4f(w_log + c, wl);
    load4f(u + c, uu);
    const float w4[4] = {-__expf(wl[0]), -__expf(wl[1]), -__expf(wl[2]), -__expf(wl[3])};
    const size_t si = ((size_t)bb * PCH + j) * DD + c;
    float aa[4], bbv[4], pp[4];
    load4f(SA + si, aa); load4f(SB + si, bbv); load4f(SP + si, pp);
    const size_t base = ((size_t)bb * TT + j * CCH) * DD + c;
#pragma unroll 4
    for (int t = 0; t < CCH; ++t) {
        const size_t o = base + (size_t)t * DD;
        float kt[4], vt[4], rt[4];
        load4f(k + o, kt);
        load4f(v + o, vt);
        load4f(r + o, rt);
        __hip_bfloat16 ob[4];
#pragma unroll
        for (int e = 0; e < 4; ++e) {
            const float ww = uu[e] + kt[e];
            const float pm = fmaxf(pp[e], ww);
            const float e1 = __expf(pp[e] - pm);
            const float e2 = __expf(ww - pm);
            const float ov = __fdividef(e1 * aa[e] + e2 * vt[e], e1 * bbv[e] + e2);
            ob[e] = f2bf(rt[e] * ov);
            const float ww2 = pp[e] + w4[e];
            const float p2  = fmaxf(ww2, kt[e]);
            const float e1b = __expf(ww2 - p2);
            const float e2b = __expf(kt[e] - p2);
            aa[e]  = e1b * aa[e]  + e2b * vt[e];
            bbv[e] = e1b * bbv[e] + e2b;
            pp[e]  = p2;
        }
        *reinterpret_cast<ushort4*>(&rw[o]) = *reinterpret_cast<const ushort4*>(ob);
    }
}

// ---------------------------------------------------------------------------
extern "C" void kernel_launch(void* const* d_in, const int* in_sizes, int n_in,
                              void* d_out, int out_size, void* d_ws, size_t ws_size,
                              hipStream_t stream)
{
    (void)in_sizes; (void)n_in; (void)out_size;
    const float* x     = (const float*)d_in[0];
    const float* ln1_g = (const float*)d_in[3];
    const float* ln1_b = (const float*)d_in[4];
    const float* ln2_g = (const float*)d_in[5];
    const float* ln2_b = (const float*)d_in[6];
    const float* mu_k  = (const float*)d_in[7];
    const float* mu_v  = (const float*)d_in[8];
    const float* mu_r  = (const float*)d_in[9];
    const float* w_log = (const float*)d_in[10];
    const float* u     = (const float*)d_in[11];
    const float* Wk    = (const float*)d_in[12];
    const float* Wv    = (const float*)d_in[13];
    const float* Wr    = (const float*)d_in[14];
    const float* Wo    = (const float*)d_in[15];
    const float* cmu_k = (const float*)d_in[16];
    const float* cmu_r = (const float*)d_in[17];
    const float* Ck    = (const float*)d_in[18];
    const float* Cv    = (const float*)d_in[19];
    const float* Cr    = (const float*)d_in[20];
    float* out = (float*)d_out;

    const size_t ND = (size_t)NROWS * DD;
    const size_t SL = ND * 2;
    const size_t WBYTES = (size_t)(5 * DW + 2 * DH) * 2;
    const size_t NSTATE = (size_t)BBATCH * PCH * DD;
    const size_t TAIL = WBYTES + 2 * (size_t)NROWS * sizeof(float)
                      + 3 * NSTATE * sizeof(float);
    int nslots;
    if      (ws_size >= 7 * SL + TAIL) nslots = 7;
    else if (ws_size >= 6 * SL + TAIL) nslots = 6;
    else if (ws_size >= 5 * SL + TAIL) nslots = 5;
    else return;

    char* w = (char*)d_ws;
    __hip_bfloat16* S0 = (__hip_bfloat16*)(w);
    __hip_bfloat16* S1 = (__hip_bfloat16*)(w + 1 * SL);
    __hip_bfloat16* S2 = (__hip_bfloat16*)(w + 2 * SL);
    __hip_bfloat16* S3 = (__hip_bfloat16*)(w + 3 * SL);
    __hip_bfloat16* S4 = (__hip_bfloat16*)(w + 4 * SL);
    __hip_bfloat16* S5 = (__hip_bfloat16*)(w + 5 * SL);
    __hip_bfloat16* WB  = (__hip_bfloat16*)(w + (size_t)nslots * SL);
    __hip_bfloat16* WkB = WB;
    __hip_bfloat16* WvB = WB + 1ull * DW;
    __hip_bfloat16* WrB = WB + 2ull * DW;
    __hip_bfloat16* WoB = WB + 3ull * DW;
    __hip_bfloat16* CrB = WB + 4ull * DW;
    __hip_bfloat16* CkB = WB + 5ull * DW;
    __hip_bfloat16* CvB = CkB + DH;
    float* meanB = (float*)(w + (size_t)nslots * SL + WBYTES);
    float* rstdB = meanB + NROWS;
    float* SAb = rstdB + NROWS;
    float* SBb = SAb + NSTATE;
    float* SPb = SBb + NSTATE;

    const int LN_GRID  = NROWS / 4;            // 4096
    const int MIX_GRID = (int)(ND / 2048);     // 6144 (8 ch/thread)
    const dim3 g768(NROWS / BM, DD / BN);      // (128, 6)
    const dim3 g1536(NROWS / BM, HHALF / BN);  // (128, 12) fallback FFN halves
    const dim3 gCk(NROWS / BM, HIDN / BN);     // (128, 24)
    const dim3 gCrCk(NROWS / BM, HIDN / BN + DD / BN);  // (128, 30) batched
    const dim3 gqkv3(NROWS / BM, DD / BN, 3);
    const dim3 gqkv2(NROWS / BM, DD / BN, 2);
    const dim3 gwkv(PCH, BBATCH);              // (16,16), 192 thr (4 ch/thread)
    const int SCANJ_GRID = (BBATCH * DD / 4) / 256;  // 12

    cvt_all<<<7488, 256, 0, stream>>>(Wk, Wv, Wr, Wo, Cr, Ck, Cv, WB);

    ln_stats_k<float><<<LN_GRID, 256, 0, stream>>>(x, meanB, rstdB);
    mix_k<float, 3><<<MIX_GRID, 256, 0, stream>>>(x, meanB, rstdB, ln1_g, ln1_b,
                                                  mu_k, mu_v, mu_r, S0, S1, S2);

    if (nslots == 7) {
        __hip_bfloat16* S6 = (__hip_bfloat16*)(w + 6 * SL);
        (void)S6;
        gemm_qkv<<<gqkv3, 256, 0, stream>>>(S0, S1, S2, WkB, WvB, WrB, S3, S4, S5);
        wkv_passA<<<gwkv, 192, 0, stream>>>(w_log, S3, S4, SAb, SBb, SPb);
        wkv_scanj<<<SCANJ_GRID, 256, 0, stream>>>(w_log, SAb, SBb, SPb);
        wkv_passB<<<gwkv, 192, 0, stream>>>(w_log, u, S3, S4, S5, S1, SAb, SBb, SPb); // rw->S1
        gemm_bt<2><<<g768, 256, 0, stream>>>(S1, WoB, DD, DD, DD, S2, nullptr,
                                             nullptr, nullptr, x, nullptr);  // h->S2
        ln_stats_k<__hip_bfloat16><<<LN_GRID, 256, 0, stream>>>(S2, meanB, rstdB);
        mix_k<__hip_bfloat16, 2><<<MIX_GRID, 256, 0, stream>>>(S2, meanB, rstdB, ln2_g, ln2_b,
                                                               cmu_k, nullptr, cmu_r,
                                                               S0, nullptr, S1); // xk2->S0, xr2->S1
        // batched: Ck (S0 -> kk in S3..S6 bf16 relu^2) + Cr (S1 -> gate fp32 in out)
        gemm_crck<<<gCrCk, 256, 0, stream>>>(S0, CkB, S3, S1, CrB, out);
        // final: out = h + gate*acc + x  (gate read from out, own tile only)
        gemm_bt<6><<<g768, 256, 0, stream>>>(S3, CvB, HIDN, HIDN, DD,
                                             nullptr, out, nullptr, S2, x, out);
    } else if (nslots == 6) {
        gemm_qkv<<<gqkv3, 256, 0, stream>>>(S0, S1, S2, WkB, WvB, WrB, S3, S4, S5);
        wkv_passA<<<gwkv, 192, 0, stream>>>(w_log, S3, S4, SAb, SBb, SPb);
        wkv_scanj<<<SCANJ_GRID, 256, 0, stream>>>(w_log, SAb, SBb, SPb);
        wkv_passB<<<gwkv, 192, 0, stream>>>(w_log, u, S3, S4, S5, S0, SAb, SBb, SPb); // rw->S0
        gemm_bt<2><<<g768, 256, 0, stream>>>(S0, WoB, DD, DD, DD, S1, nullptr,
                                             nullptr, nullptr, x, nullptr);  // h->S1
        ln_stats_k<__hip_bfloat16><<<LN_GRID, 256, 0, stream>>>(S1, meanB, rstdB);
        mix_k<__hip_bfloat16, 2><<<MIX_GRID, 256, 0, stream>>>(S1, meanB, rstdB, ln2_g, ln2_b,
                                                               cmu_k, nullptr, cmu_r,
                                                               S0, nullptr, S2);
        // gate as fp32 parked in d_out (each MODE-6 block reads only its own tile)
        gemm_bt<7><<<g768, 256, 0, stream>>>(S2, CrB, DD, DD, DD, nullptr, out,
                                             nullptr, nullptr, nullptr, nullptr);
        gemm_bt<3><<<gCk, 256, 0, stream>>>(S0, CkB, DD, DD, HIDN,
                                            S2, nullptr, nullptr, nullptr, nullptr, nullptr);
        gemm_bt<6><<<g768, 256, 0, stream>>>(S2, CvB, HIDN, HIDN, DD,
                                             nullptr, out, nullptr, S1, x, out);
    } else {
        // 5-slot fallback: legacy verified schedule
        gemm_qkv<<<gqkv2, 256, 0, stream>>>(S0, S1, nullptr, WkB, WvB, nullptr,
                                            S3, S4, nullptr);       // k->S3, v->S4
        gemm_bt<1><<<g768, 256, 0, stream>>>(S2, WrB, DD, DD, DD, S0, nullptr,
                                             nullptr, nullptr, nullptr, nullptr); // r->S0
        wkv_passA<<<gwkv, 192, 0, stream>>>(w_log, S3, S4, SAb, SBb, SPb);
        wkv_scanj<<<SCANJ_GRID, 256, 0, stream>>>(w_log, SAb, SBb, SPb);
        wkv_passB<<<gwkv, 192, 0, stream>>>(w_log, u, S3, S4, S0, S1, SAb, SBb, SPb); // rw->S1
        gemm_bt<2><<<g768, 256, 0, stream>>>(S1, WoB, DD, DD, DD, S2, nullptr,
                                             nullptr, nullptr, x, nullptr);       // h->S2
        ln_stats_k<__hip_bfloat16><<<LN_GRID, 256, 0, stream>>>(S2, meanB, rstdB);
        mix_k<__hip_bfloat16, 2><<<MIX_GRID, 256, 0, stream>>>(S2, meanB, rstdB, ln2_g, ln2_b,
                                                               cmu_k, nullptr, cmu_r,
                                                               S0, nullptr, S3);
        gemm_bt<1><<<g768, 256, 0, stream>>>(S3, CrB, DD, DD, DD, S1, nullptr,
                                             nullptr, nullptr, nullptr, nullptr); // cr->S1
        __hip_bfloat16* kk = S3;  // FFN in two 1536-wide halves (kk in S3+S4)
        gemm_bt<3><<<g1536, 256, 0, stream>>>(S0, CkB, DD, DD, HHALF,
                                              kk, nullptr, nullptr, nullptr, nullptr, nullptr);
        gemm_bt<4><<<g768, 256, 0, stream>>>(kk, CvB, HHALF, HIDN, DD,
                                             nullptr, out, S1, S2, x, nullptr);
        gemm_bt<3><<<g1536, 256, 0, stream>>>(S0, CkB + (size_t)HHALF * DD, DD, DD, HHALF,
                                              kk, nullptr, nullptr, nullptr, nullptr, nullptr);
        gemm_bt<5><<<g768, 256, 0, stream>>>(kk, CvB + HHALF, HHALF, HIDN, DD,
                                             nullptr, out, S1, nullptr, nullptr, nullptr);
    }
}

// Round 8
// 539.342 us; speedup vs baseline: 1.1635x; 1.0764x over previous
//
#include <hip/hip_runtime.h>
#include <hip/hip_bf16.h>

// Problem constants (fixed by the reference)
#define DD   768
#define TT   1024
#define BBATCH 16
#define NROWS (BBATCH * TT)   // 16384
#define HIDN 3072
#define HHALF 1536
#define HH 32
#define WW 32
#define DW  (DD * DD)         // 589824
#define DH  (DD * HIDN)       // 2359296
#define CCH 64                // wkv chunk length
#define PCH (TT / CCH)        // 16 chunks

typedef float  floatx4 __attribute__((ext_vector_type(4)));
typedef __bf16 bf16x8  __attribute__((ext_vector_type(8)));

__device__ __forceinline__ float bf2f(__hip_bfloat16 v) { return __bfloat162float(v); }
__device__ __forceinline__ __hip_bfloat16 f2bf(float v) { return __float2bfloat16(v); }
__device__ __forceinline__ float toF(__hip_bfloat16 v) { return __bfloat162float(v); }
__device__ __forceinline__ float toF(float v) { return v; }

__device__ __forceinline__ void load4f(const float* __restrict__ p, float o[4]) {
    const float4 v = *reinterpret_cast<const float4*>(p);
    o[0] = v.x; o[1] = v.y; o[2] = v.z; o[3] = v.w;
}
__device__ __forceinline__ void load4f(const __hip_bfloat16* __restrict__ p, float o[4]) {
    const ushort4 v = *reinterpret_cast<const ushort4*>(p);
    o[0] = bf2f(__hip_bfloat16_raw{v.x});
    o[1] = bf2f(__hip_bfloat16_raw{v.y});
    o[2] = bf2f(__hip_bfloat16_raw{v.z});
    o[3] = bf2f(__hip_bfloat16_raw{v.w});
}
__device__ __forceinline__ void load8f(const float* __restrict__ p, float o[8]) {
    load4f(p, o); load4f(p + 4, o + 4);
}
__device__ __forceinline__ void load8f(const __hip_bfloat16* __restrict__ p, float o[8]) {
    const uint4 v = *reinterpret_cast<const uint4*>(p);
    const unsigned short* s = reinterpret_cast<const unsigned short*>(&v);
#pragma unroll
    for (int e = 0; e < 8; ++e) o[e] = bf2f(__hip_bfloat16_raw{s[e]});
}

// global -> LDS direct DMA, 16 B per lane, dest = uniform base + lane*16
#define GL2LDS(gp, lp)  __builtin_amdgcn_global_load_lds(                     \
    (const __attribute__((address_space(1))) void*)(gp),                      \
    (__attribute__((address_space(3))) void*)(lp), 16, 0, 0)

// ---------------------------------------------------------------------------
// fp32 -> bf16 conversion of ALL weights in one dispatch (7 segments).
// ---------------------------------------------------------------------------
__global__ __launch_bounds__(256)
void cvt_all(const float* __restrict__ w0, const float* __restrict__ w1,
             const float* __restrict__ w2, const float* __restrict__ w3,
             const float* __restrict__ w4, const float* __restrict__ w5,
             const float* __restrict__ w6, __hip_bfloat16* __restrict__ dst)
{
    const int b = blockIdx.x;
    const float* s; size_t dofs; int rel;
    if (b < 2880) {            // 5 x 576 blocks of DW
        const int seg = b / 576; rel = b - seg * 576;
        s = seg == 0 ? w0 : seg == 1 ? w1 : seg == 2 ? w2 : seg == 3 ? w3 : w4;
        dofs = (size_t)seg * DW;
    } else if (b < 5184) {     // Ck
        rel = b - 2880; s = w5; dofs = 5ull * DW;
    } else {                   // Cv
        rel = b - 5184; s = w6; dofs = 5ull * DW + DH;
    }
    const int i = rel * 1024 + threadIdx.x * 4;
    const float4 v = *reinterpret_cast<const float4*>(s + i);
    __hip_bfloat16 o[4] = {f2bf(v.x), f2bf(v.y), f2bf(v.z), f2bf(v.w)};
    *reinterpret_cast<ushort4*>(&dst[dofs + i]) = *reinterpret_cast<const ushort4*>(o);
}

// ---------------------------------------------------------------------------
// Per-row LN stats: one wave per row, vectorized.
// ---------------------------------------------------------------------------
template <typename TIN>
__global__ __launch_bounds__(256)
void ln_stats_k(const TIN* __restrict__ x,
                float* __restrict__ mean, float* __restrict__ rstd)
{
    const int row  = blockIdx.x * 4 + (threadIdx.x >> 6);
    const int lane = threadIdx.x & 63;
    const TIN* xr = x + (size_t)row * DD;
    float s1 = 0.f, s2 = 0.f;
#pragma unroll
    for (int q = 0; q < 3; ++q) {
        float v4[4];
        load4f(xr + 4 * lane + 256 * q, v4);
#pragma unroll
        for (int e = 0; e < 4; ++e) { s1 += v4[e]; s2 += v4[e] * v4[e]; }
    }
#pragma unroll
    for (int off = 32; off > 0; off >>= 1) {
        s1 += __shfl_down(s1, off);
        s2 += __shfl_down(s2, off);
    }
    if (lane == 0) {
        const float m = s1 * (1.f / DD);
        mean[row] = m;
        rstd[row] = rsqrtf(s2 * (1.f / DD) - m * m + 1e-5f);
    }
}

// ---------------------------------------------------------------------------
// LN-on-the-fly + q_shift + token-mix, 8 channels/thread (uint4 bf16 stores).
// ---------------------------------------------------------------------------
template <typename TIN, int NOUT>
__global__ __launch_bounds__(256)
void mix_k(const TIN* __restrict__ x,
           const float* __restrict__ mean, const float* __restrict__ rstd,
           const float* __restrict__ g, const float* __restrict__ b,
           const float* __restrict__ muk,
           const float* __restrict__ muv,
           const float* __restrict__ mur,
           __hip_bfloat16* __restrict__ xk,
           __hip_bfloat16* __restrict__ xv,
           __hip_bfloat16* __restrict__ xr)
{
    const size_t i8 = ((size_t)blockIdx.x * 256 + threadIdx.x) * 8;
    const int c  = (int)(i8 % DD);
    const int n  = (int)((i8 / DD) % TT);
    const int bb = (int)(i8 / ((size_t)DD * TT));
    const int y = n >> 5, xp = n & 31;
    const int grow = bb * TT + n;

    const int grp = c / (DD / 4);
    int ny = y, nx = xp; bool ok;
    if      (grp == 0) { nx = xp - 1; ok = xp > 0;      }
    else if (grp == 1) { nx = xp + 1; ok = xp < WW - 1; }
    else if (grp == 2) { ny = y - 1;  ok = y > 0;       }
    else               { ny = y + 1;  ok = y < HH - 1;  }

    float gg[8], bbv[8];
    load8f(g + c, gg); load8f(b + c, bbv);

    float xc[8];
    load8f(x + (size_t)grow * DD + c, xc);
    const float m = mean[grow], rs = rstd[grow];
    float av[8], sx[8] = {0.f, 0.f, 0.f, 0.f, 0.f, 0.f, 0.f, 0.f};
#pragma unroll
    for (int e = 0; e < 8; ++e) av[e] = (xc[e] - m) * rs * gg[e] + bbv[e];

    if (ok) {
        const int nrow = bb * TT + ny * WW + nx;
        float xn[8];
        load8f(x + (size_t)nrow * DD + c, xn);
        const float m2 = mean[nrow], rs2 = rstd[nrow];
#pragma unroll
        for (int e = 0; e < 8; ++e) sx[e] = (xn[e] - m2) * rs2 * gg[e] + bbv[e];
    }

    float mk[8], mr[8];
    load8f(muk + c, mk); load8f(mur + c, mr);
    __hip_bfloat16 ok8[8], or8[8];
#pragma unroll
    for (int e = 0; e < 8; ++e) {
        ok8[e] = f2bf(av[e] * mk[e] + sx[e] * (1.f - mk[e]));
        or8[e] = f2bf(av[e] * mr[e] + sx[e] * (1.f - mr[e]));
    }
    *reinterpret_cast<uint4*>(&xk[i8]) = *reinterpret_cast<const uint4*>(ok8);
    *reinterpret_cast<uint4*>(&xr[i8]) = *reinterpret_cast<const uint4*>(or8);
    if (NOUT == 3) {
        float mv[8];
        load8f(muv + c, mv);
        __hip_bfloat16 ov8[8];
#pragma unroll
        for (int e = 0; e < 8; ++e)
            ov8[e] = f2bf(av[e] * mv[e] + sx[e] * (1.f - mv[e]));
        *reinterpret_cast<uint4*>(&xv[i8]) = *reinterpret_cast<const uint4*>(ov8);
    }
}

// ---------------------------------------------------------------------------
// Shared epilogue transpose + MODE stores
// ---------------------------------------------------------------------------
__device__ __forceinline__ void xpose_band(const floatx4 accRow[4], float* scr,
                                           int lane, float cv[16])
{
    const int l15 = lane & 15, quad = lane >> 4;
#pragma unroll
    for (int j = 0; j < 4; ++j)
#pragma unroll
        for (int r = 0; r < 4; ++r)
            scr[(quad * 4 + r) * 68 + j * 16 + l15] = accRow[j][r];
    const int row_l = lane >> 2, cb = (lane & 3) * 16;
#pragma unroll
    for (int q = 0; q < 4; ++q)
        *reinterpret_cast<float4*>(&cv[q * 4]) =
            *reinterpret_cast<const float4*>(&scr[row_l * 68 + cb + q * 4]);
}

// MODE: 1=bf16(sigmoid), 2=bf16(acc + xf32), 3=bf16(relu^2),
//       4=f32 out = h + s*acc + x   (s bf16)
//       5=f32 out += s*acc
//       6=f32 out = h + gf*acc + x  (gf fp32; may alias out — own tile only)
//       7=f32 out = sigmoid(acc)
template <int MODE>
__device__ __forceinline__ void mode_store(
    const float cv[16], size_t idx,
    __hip_bfloat16* __restrict__ outB, float* __restrict__ outF,
    const __hip_bfloat16* __restrict__ auxS, const __hip_bfloat16* __restrict__ auxH,
    const float* __restrict__ auxX, const float* __restrict__ auxG)
{
    if (MODE == 1 || MODE == 3) {
        __hip_bfloat16 ob[16];
#pragma unroll
        for (int e = 0; e < 16; ++e) {
            float v = cv[e];
            if (MODE == 1) v = 1.f / (1.f + __expf(-v));
            else { v = fmaxf(v, 0.f); v = v * v; }
            ob[e] = f2bf(v);
        }
        *reinterpret_cast<uint4*>(&outB[idx])     = *reinterpret_cast<const uint4*>(&ob[0]);
        *reinterpret_cast<uint4*>(&outB[idx + 8]) = *reinterpret_cast<const uint4*>(&ob[8]);
    } else if (MODE == 2) {
        float xv[16];
#pragma unroll
        for (int q = 0; q < 4; ++q)
            *reinterpret_cast<float4*>(&xv[q * 4]) =
                *reinterpret_cast<const float4*>(&auxX[idx + q * 4]);
        __hip_bfloat16 ob[16];
#pragma unroll
        for (int e = 0; e < 16; ++e) ob[e] = f2bf(cv[e] + xv[e]);
        *reinterpret_cast<uint4*>(&outB[idx])     = *reinterpret_cast<const uint4*>(&ob[0]);
        *reinterpret_cast<uint4*>(&outB[idx + 8]) = *reinterpret_cast<const uint4*>(&ob[8]);
    } else if (MODE == 4) {
        unsigned short hs[16], ss[16]; float xv[16], ov[16];
        *reinterpret_cast<uint4*>(&hs[0]) = *reinterpret_cast<const uint4*>(&auxH[idx]);
        *reinterpret_cast<uint4*>(&hs[8]) = *reinterpret_cast<const uint4*>(&auxH[idx + 8]);
        *reinterpret_cast<uint4*>(&ss[0]) = *reinterpret_cast<const uint4*>(&auxS[idx]);
        *reinterpret_cast<uint4*>(&ss[8]) = *reinterpret_cast<const uint4*>(&auxS[idx + 8]);
#pragma unroll
        for (int q = 0; q < 4; ++q)
            *reinterpret_cast<float4*>(&xv[q * 4]) =
                *reinterpret_cast<const float4*>(&auxX[idx + q * 4]);
#pragma unroll
        for (int e = 0; e < 16; ++e)
            ov[e] = bf2f(__hip_bfloat16_raw{hs[e]})
                  + bf2f(__hip_bfloat16_raw{ss[e]}) * cv[e] + xv[e];
#pragma unroll
        for (int q = 0; q < 4; ++q)
            *reinterpret_cast<float4*>(&outF[idx + q * 4]) =
                *reinterpret_cast<const float4*>(&ov[q * 4]);
    } else if (MODE == 5) {
        unsigned short ss[16]; float ov[16];
        *reinterpret_cast<uint4*>(&ss[0]) = *reinterpret_cast<const uint4*>(&auxS[idx]);
        *reinterpret_cast<uint4*>(&ss[8]) = *reinterpret_cast<const uint4*>(&auxS[idx + 8]);
#pragma unroll
        for (int q = 0; q < 4; ++q)
            *reinterpret_cast<float4*>(&ov[q * 4]) =
                *reinterpret_cast<const float4*>(&outF[idx + q * 4]);
#pragma unroll
        for (int e = 0; e < 16; ++e)
            ov[e] += bf2f(__hip_bfloat16_raw{ss[e]}) * cv[e];
#pragma unroll
        for (int q = 0; q < 4; ++q)
            *reinterpret_cast<float4*>(&outF[idx + q * 4]) =
                *reinterpret_cast<const float4*>(&ov[q * 4]);
    } else if (MODE == 6) {
        unsigned short hs[16]; float xv[16], gf[16], ov[16];
        *reinterpret_cast<uint4*>(&hs[0]) = *reinterpret_cast<const uint4*>(&auxH[idx]);
        *reinterpret_cast<uint4*>(&hs[8]) = *reinterpret_cast<const uint4*>(&auxH[idx + 8]);
#pragma unroll
        for (int q = 0; q < 4; ++q) {
            *reinterpret_cast<float4*>(&xv[q * 4]) =
                *reinterpret_cast<const float4*>(&auxX[idx + q * 4]);
            *reinterpret_cast<float4*>(&gf[q * 4]) =
                *reinterpret_cast<const float4*>(&auxG[idx + q * 4]);
        }
#pragma unroll
        for (int e = 0; e < 16; ++e)
            ov[e] = bf2f(__hip_bfloat16_raw{hs[e]}) + gf[e] * cv[e] + xv[e];
#pragma unroll
        for (int q = 0; q < 4; ++q)
            *reinterpret_cast<float4*>(&outF[idx + q * 4]) =
                *reinterpret_cast<const float4*>(&ov[q * 4]);
    } else {  // MODE 7
        float ov[16];
#pragma unroll
        for (int e = 0; e < 16; ++e)
            ov[e] = 1.f / (1.f + __expf(-cv[e]));
#pragma unroll
        for (int q = 0; q < 4; ++q)
            *reinterpret_cast<float4*>(&outF[idx + q * 4]) =
                *reinterpret_cast<const float4*>(&ov[q * 4]);
    }
}

// ---------------------------------------------------------------------------
// 128x128 GEMM core (proven): 4 waves (2x2 of 64x64), BK=64, global_load_lds
// staging with XOR col-group swizzle (0 bank conflicts).
// ---------------------------------------------------------------------------
#define BM 128
#define BN 128
#define BKK 64

__device__ __forceinline__ void gemm_core(
    const __hip_bfloat16* __restrict__ A, const __hip_bfloat16* __restrict__ W,
    int K, int Wstr, int bm, int bn, unsigned short* lds, floatx4 acc[4][4])
{
    const int tid  = threadIdx.x;
    const int lane = tid & 63, wid = tid >> 6;
    const int l15  = lane & 15, quad = lane >> 4;
    const int m0   = (wid & 1) * 64;
    const int n0   = (wid >> 1) * 64;
    const int srow  = lane >> 3;
    const int gcolg = (lane & 7) ^ srow;
    const int s0    = wid * 4;
    const int swzbase = l15 & 7;

    for (int k0 = 0; k0 < K; k0 += BKK) {
#pragma unroll
        for (int t = 0; t < 4; ++t) {
            const int s   = s0 + t;
            const int row = s * 8 + srow;
            GL2LDS(A + (size_t)(bm * BM + row) * K    + k0 + gcolg * 8,
                   &lds[s * 512]);
            GL2LDS(W + (size_t)(bn * BN + row) * Wstr + k0 + gcolg * 8,
                   &lds[8192 + s * 512]);
        }
        __syncthreads();
#pragma unroll
        for (int kk = 0; kk < BKK; kk += 32) {
            const int swz = (((kk >> 3) + quad) ^ swzbase) * 8;
            bf16x8 afr[4], bfr[4];
#pragma unroll
            for (int i = 0; i < 4; ++i)
                afr[i] = *reinterpret_cast<const bf16x8*>(
                    &lds[(m0 + i * 16 + l15) * BKK + swz]);
#pragma unroll
            for (int j = 0; j < 4; ++j)
                bfr[j] = *reinterpret_cast<const bf16x8*>(
                    &lds[8192 + (n0 + j * 16 + l15) * BKK + swz]);
#pragma unroll
            for (int i = 0; i < 4; ++i)
#pragma unroll
                for (int j = 0; j < 4; ++j)
                    acc[i][j] = __builtin_amdgcn_mfma_f32_16x16x32_bf16(
                        afr[i], bfr[j], acc[i][j], 0, 0, 0);
        }
        __syncthreads();
    }
}

template <int MODE>
__global__ __launch_bounds__(256, 2)
void gemm_bt(const __hip_bfloat16* __restrict__ A,
             const __hip_bfloat16* __restrict__ W,
             int K, int Wstr, int Nn,
             __hip_bfloat16* __restrict__ outB,
             float* __restrict__ outF,
             const __hip_bfloat16* __restrict__ auxS,
             const __hip_bfloat16* __restrict__ auxH,
             const float* __restrict__ auxX,
             const float* __restrict__ auxG)
{
    __shared__ __align__(16) unsigned short lds[16384];
    const int bm = blockIdx.x, bn = blockIdx.y;
    const int tid = threadIdx.x, lane = tid & 63, wid = tid >> 6;
    const int m0 = (wid & 1) * 64, n0 = (wid >> 1) * 64;

    floatx4 acc[4][4];
#pragma unroll
    for (int i = 0; i < 4; ++i)
#pragma unroll
        for (int j = 0; j < 4; ++j)
            acc[i][j] = floatx4{0.f, 0.f, 0.f, 0.f};

    gemm_core(A, W, K, Wstr, bm, bn, lds, acc);

    float* scr = reinterpret_cast<float*>(lds) + wid * 1088;
    const int row_l = lane >> 2, cb = (lane & 3) * 16;
#pragma unroll
    for (int i = 0; i < 4; ++i) {
        float cv[16];
        xpose_band(acc[i], scr, lane, cv);
        const int grow = bm * BM + m0 + i * 16 + row_l;
        const int gcol = bn * BN + n0 + cb;
        const size_t idx = (size_t)grow * Nn + gcol;
        mode_store<MODE>(cv, idx, outB, outF, auxS, auxH, auxX, auxG);
    }
}

// Batched QKV: z=0 k, z=1 v, z=2 r=sigmoid
__global__ __launch_bounds__(256, 2)
void gemm_qkv(const __hip_bfloat16* __restrict__ A0, const __hip_bfloat16* __restrict__ A1,
              const __hip_bfloat16* __restrict__ A2,
              const __hip_bfloat16* __restrict__ W0, const __hip_bfloat16* __restrict__ W1,
              const __hip_bfloat16* __restrict__ W2,
              __hip_bfloat16* __restrict__ O0, __hip_bfloat16* __restrict__ O1,
              __hip_bfloat16* __restrict__ O2)
{
    __shared__ __align__(16) unsigned short lds[16384];
    const int z = blockIdx.z;
    const __hip_bfloat16* A = z == 0 ? A0 : z == 1 ? A1 : A2;
    const __hip_bfloat16* W = z == 0 ? W0 : z == 1 ? W1 : W2;
    __hip_bfloat16*       O = z == 0 ? O0 : z == 1 ? O1 : O2;
    const int bm = blockIdx.x, bn = blockIdx.y;
    const int tid = threadIdx.x, lane = tid & 63, wid = tid >> 6;
    const int m0 = (wid & 1) * 64, n0 = (wid >> 1) * 64;

    floatx4 acc[4][4];
#pragma unroll
    for (int i = 0; i < 4; ++i)
#pragma unroll
        for (int j = 0; j < 4; ++j)
            acc[i][j] = floatx4{0.f, 0.f, 0.f, 0.f};

    gemm_core(A, W, DD, DD, bm, bn, lds, acc);

    float* scr = reinterpret_cast<float*>(lds) + wid * 1088;
    const int row_l = lane >> 2, cb = (lane & 3) * 16;
#pragma unroll
    for (int i = 0; i < 4; ++i) {
        float cv[16];
        xpose_band(acc[i], scr, lane, cv);
        const int grow = bm * BM + m0 + i * 16 + row_l;
        const int gcol = bn * BN + n0 + cb;
        const size_t idx = (size_t)grow * DD + gcol;
        __hip_bfloat16 ob[16];
#pragma unroll
        for (int e = 0; e < 16; ++e) {
            float v = cv[e];
            if (z == 2) v = 1.f / (1.f + __expf(-v));
            ob[e] = f2bf(v);
        }
        *reinterpret_cast<uint4*>(&O[idx])     = *reinterpret_cast<const uint4*>(&ob[0]);
        *reinterpret_cast<uint4*>(&O[idx + 8]) = *reinterpret_cast<const uint4*>(&ob[8]);
    }
}

// ---------------------------------------------------------------------------
// WKV parallel scan over T (chunked two-pass), 4 channels/thread.
// ---------------------------------------------------------------------------
__global__ __launch_bounds__(192)
void wkv_passA(const float* __restrict__ w_log,
               const __hip_bfloat16* __restrict__ k,
               const __hip_bfloat16* __restrict__ v,
               float* __restrict__ SA, float* __restrict__ SB,
               float* __restrict__ SP)
{
    const int c  = threadIdx.x * 4;   // 0..764
    const int j  = blockIdx.x;        // chunk
    const int bb = blockIdx.y;        // batch
    float wl[4];
    load4f(w_log + c, wl);
    const float w4[4] = {-__expf(wl[0]), -__expf(wl[1]), -__expf(wl[2]), -__expf(wl[3])};
    const size_t base = ((size_t)bb * TT + j * CCH) * DD + c;
    float a[4] = {0.f, 0.f, 0.f, 0.f}, b2[4] = {0.f, 0.f, 0.f, 0.f};
    float p[4] = {-1e30f, -1e30f, -1e30f, -1e30f};
#pragma unroll 4
    for (int t = 0; t < CCH; ++t) {
        const size_t o = base + (size_t)t * DD;
        float kt[4], vt[4];
        load4f(k + o, kt);
        load4f(v + o, vt);
#pragma unroll
        for (int e = 0; e < 4; ++e) {
            const float ww2 = p[e] + w4[e];
            const float p2  = fmaxf(ww2, kt[e]);
            const float e1  = __expf(ww2 - p2);
            const float e2  = __expf(kt[e] - p2);
            a[e]  = e1 * a[e]  + e2 * vt[e];
            b2[e] = e1 * b2[e] + e2;
            p[e]  = p2;
        }
    }
    const size_t si = ((size_t)bb * PCH + j) * DD + c;
    *reinterpret_cast<float4*>(&SA[si]) = float4{a[0], a[1], a[2], a[3]};
    *reinterpret_cast<float4*>(&SB[si]) = float4{b2[0], b2[1], b2[2], b2[3]};
    *reinterpret_cast<float4*>(&SP[si]) = float4{p[0], p[1], p[2], p[3]};
}

__global__ __launch_bounds__(256)
void wkv_scanj(const float* __restrict__ w_log,
               float* __restrict__ SA, float* __restrict__ SB,
               float* __restrict__ SP)
{
    const int idx = blockIdx.x * 256 + threadIdx.x;  // 0..B*D/4-1
    const int c = (idx * 4) % DD, bb = (idx * 4) / DD;
    float wl[4];
    load4f(w_log + c, wl);
    float wC[4];
#pragma unroll
    for (int e = 0; e < 4; ++e) wC[e] = -__expf(wl[e]) * (float)CCH;
    float a[4] = {0.f, 0.f, 0.f, 0.f}, b2[4] = {0.f, 0.f, 0.f, 0.f};
    float p[4] = {-1e30f, -1e30f, -1e30f, -1e30f};
#pragma unroll
    for (int j = 0; j < PCH; ++j) {
        const size_t si = ((size_t)bb * PCH + j) * DD + c;
        float aj[4], bj[4], pj[4];
        load4f(SA + si, aj); load4f(SB + si, bj); load4f(SP + si, pj);
        *reinterpret_cast<float4*>(&SA[si]) = float4{a[0], a[1], a[2], a[3]};
        *reinterpret_cast<float4*>(&SB[si]) = float4{b2[0], b2[1], b2[2], b2[3]};
        *reinterpret_cast<float4*>(&SP[si]) = float4{p[0], p[1], p[2], p[3]};
#pragma unroll
        for (int e = 0; e < 4; ++e) {
            const float pd = p[e] + wC[e];
            const float pn = fmaxf(pd, pj[e]);
            const float e1 = __expf(pd - pn);
            const float e2 = __expf(pj[e] - pn);
            a[e]  = e1 * a[e]  + e2 * aj[e];
            b2[e] = e1 * b2[e] + e2 * bj[e];
            p[e]  = pn;
        }
    }
}

__global__ __launch_bounds__(192)
void wkv_passB(const float* __restrict__ w_log, const float* __restrict__ u,
               const __hip_bfloat16* __restrict__ k,
               const __hip_bfloat16* __restrict__ v,
               const __hip_bfloat16* __restrict__ r,
               __hip_bfloat16* __restrict__ rw,
               const float* __restrict__ SA, const float* __restrict__ SB,
               const float* __restrict__ SP)
{
    const int c  = threadIdx.x * 4;
    const int j  = blockIdx.x;
    const int bb = blockIdx.y;
    float wl[4], uu[4];
    load4f(w_log + c, wl);
    load4f(u + c, uu);
    const float w4[4] = {-__expf(wl[0]), -__expf(wl[1]), -__expf(wl[2]), -__expf(wl[3])};
    const size_t si = ((size_t)bb * PCH + j) * DD + c;
    float aa[4], bbv[4], pp[4];
    load4f(SA + si, aa); load4f(SB + si, bbv); load4f(SP + si, pp);
    const size_t base = ((size_t)bb * TT + j * CCH) * DD + c;
#pragma unroll 4
    for (int t = 0; t < CCH; ++t) {
        const size_t o = base + (size_t)t * DD;
        float kt[4], vt[4], rt[4];
        load4f(k + o, kt);
        load4f(v + o, vt);
        load4f(r + o, rt);
        __hip_bfloat16 ob[4];
#pragma unroll
        for (int e = 0; e < 4; ++e) {
            const float ww = uu[e] + kt[e];
            const float pm = fmaxf(pp[e], ww);
            const float e1 = __expf(pp[e] - pm);
            const float e2 = __expf(ww - pm);
            const float ov = __fdividef(e1 * aa[e] + e2 * vt[e], e1 * bbv[e] + e2);
            ob[e] = f2bf(rt[e] * ov);
            const float ww2 = pp[e] + w4[e];
            const float p2  = fmaxf(ww2, kt[e]);
            const float e1b = __expf(ww2 - p2);
            const float e2b = __expf(kt[e] - p2);
            aa[e]  = e1b * aa[e]  + e2b * vt[e];
            bbv[e] = e1b * bbv[e] + e2b;
            pp[e]  = p2;
        }
        *reinterpret_cast<ushort4*>(&rw[o]) = *reinterpret_cast<const ushort4*>(ob);
    }
}

// ---------------------------------------------------------------------------
extern "C" void kernel_launch(void* const* d_in, const int* in_sizes, int n_in,
                              void* d_out, int out_size, void* d_ws, size_t ws_size,
                              hipStream_t stream)
{
    (void)in_sizes; (void)n_in; (void)out_size;
    const float* x     = (const float*)d_in[0];
    const float* ln1_g = (const float*)d_in[3];
    const float* ln1_b = (const float*)d_in[4];
    const float* ln2_g = (const float*)d_in[5];
    const float* ln2_b = (const float*)d_in[6];
    const float* mu_k  = (const float*)d_in[7];
    const float* mu_v  = (const float*)d_in[8];
    const float* mu_r  = (const float*)d_in[9];
    const float* w_log = (const float*)d_in[10];
    const float* u     = (const float*)d_in[11];
    const float* Wk    = (const float*)d_in[12];
    const float* Wv    = (const float*)d_in[13];
    const float* Wr    = (const float*)d_in[14];
    const float* Wo    = (const float*)d_in[15];
    const float* cmu_k = (const float*)d_in[16];
    const float* cmu_r = (const float*)d_in[17];
    const float* Ck    = (const float*)d_in[18];
    const float* Cv    = (const float*)d_in[19];
    const float* Cr    = (const float*)d_in[20];
    float* out = (float*)d_out;

    const size_t ND = (size_t)NROWS * DD;
    const size_t SL = ND * 2;
    const size_t WBYTES = (size_t)(5 * DW + 2 * DH) * 2;
    const size_t NSTATE = (size_t)BBATCH * PCH * DD;
    const size_t TAIL = WBYTES + 2 * (size_t)NROWS * sizeof(float)
                      + 3 * NSTATE * sizeof(float);
    int nslots;
    if      (ws_size >= 7 * SL + TAIL) nslots = 7;
    else if (ws_size >= 6 * SL + TAIL) nslots = 6;
    else if (ws_size >= 5 * SL + TAIL) nslots = 5;
    else return;

    char* w = (char*)d_ws;
    __hip_bfloat16* S0 = (__hip_bfloat16*)(w);
    __hip_bfloat16* S1 = (__hip_bfloat16*)(w + 1 * SL);
    __hip_bfloat16* S2 = (__hip_bfloat16*)(w + 2 * SL);
    __hip_bfloat16* S3 = (__hip_bfloat16*)(w + 3 * SL);
    __hip_bfloat16* S4 = (__hip_bfloat16*)(w + 4 * SL);
    __hip_bfloat16* S5 = (__hip_bfloat16*)(w + 5 * SL);
    __hip_bfloat16* WB  = (__hip_bfloat16*)(w + (size_t)nslots * SL);
    __hip_bfloat16* WkB = WB;
    __hip_bfloat16* WvB = WB + 1ull * DW;
    __hip_bfloat16* WrB = WB + 2ull * DW;
    __hip_bfloat16* WoB = WB + 3ull * DW;
    __hip_bfloat16* CrB = WB + 4ull * DW;
    __hip_bfloat16* CkB = WB + 5ull * DW;
    __hip_bfloat16* CvB = CkB + DH;
    float* meanB = (float*)(w + (size_t)nslots * SL + WBYTES);
    float* rstdB = meanB + NROWS;
    float* SAb = rstdB + NROWS;
    float* SBb = SAb + NSTATE;
    float* SPb = SBb + NSTATE;

    const int LN_GRID  = NROWS / 4;            // 4096
    const int MIX_GRID = (int)(ND / 2048);     // 6144 (8 ch/thread)
    const dim3 g768(NROWS / BM, DD / BN);      // (128, 6)
    const dim3 g1536(NROWS / BM, HHALF / BN);  // (128, 12) fallback FFN halves
    const dim3 gCk(NROWS / BM, HIDN / BN);     // (128, 24) merged Ck
    const dim3 gqkv3(NROWS / BM, DD / BN, 3);
    const dim3 gqkv2(NROWS / BM, DD / BN, 2);
    const dim3 gwkv(PCH, BBATCH);              // (16,16), 192 thr (4 ch/thread)
    const int SCANJ_GRID = (BBATCH * DD / 4) / 256;  // 12

    cvt_all<<<7488, 256, 0, stream>>>(Wk, Wv, Wr, Wo, Cr, Ck, Cv, WB);

    ln_stats_k<float><<<LN_GRID, 256, 0, stream>>>(x, meanB, rstdB);
    mix_k<float, 3><<<MIX_GRID, 256, 0, stream>>>(x, meanB, rstdB, ln1_g, ln1_b,
                                                  mu_k, mu_v, mu_r, S0, S1, S2);

    if (nslots == 7) {
        gemm_qkv<<<gqkv3, 256, 0, stream>>>(S0, S1, S2, WkB, WvB, WrB, S3, S4, S5);
        wkv_passA<<<gwkv, 192, 0, stream>>>(w_log, S3, S4, SAb, SBb, SPb);
        wkv_scanj<<<SCANJ_GRID, 256, 0, stream>>>(w_log, SAb, SBb, SPb);
        wkv_passB<<<gwkv, 192, 0, stream>>>(w_log, u, S3, S4, S5, S1, SAb, SBb, SPb); // rw->S1
        gemm_bt<2><<<g768, 256, 0, stream>>>(S1, WoB, DD, DD, DD, S2, nullptr,
                                             nullptr, nullptr, x, nullptr);  // h->S2
        ln_stats_k<__hip_bfloat16><<<LN_GRID, 256, 0, stream>>>(S2, meanB, rstdB);
        mix_k<__hip_bfloat16, 2><<<MIX_GRID, 256, 0, stream>>>(S2, meanB, rstdB, ln2_g, ln2_b,
                                                               cmu_k, nullptr, cmu_r,
                                                               S0, nullptr, S3);
        gemm_bt<1><<<g768, 256, 0, stream>>>(S3, CrB, DD, DD, DD, S1, nullptr,
                                             nullptr, nullptr, nullptr, nullptr); // gate->S1
        // merged FFN: kk (16384 x 3072 bf16 = 100 MB) in contiguous S3..S6
        gemm_bt<3><<<gCk, 256, 0, stream>>>(S0, CkB, DD, DD, HIDN,
                                            S3, nullptr, nullptr, nullptr, nullptr, nullptr);
        gemm_bt<4><<<g768, 256, 0, stream>>>(S3, CvB, HIDN, HIDN, DD,
                                             nullptr, out, S1, S2, x, nullptr);
    } else if (nslots == 6) {
        gemm_qkv<<<gqkv3, 256, 0, stream>>>(S0, S1, S2, WkB, WvB, WrB, S3, S4, S5);
        wkv_passA<<<gwkv, 192, 0, stream>>>(w_log, S3, S4, SAb, SBb, SPb);
        wkv_scanj<<<SCANJ_GRID, 256, 0, stream>>>(w_log, SAb, SBb, SPb);
        wkv_passB<<<gwkv, 192, 0, stream>>>(w_log, u, S3, S4, S5, S0, SAb, SBb, SPb); // rw->S0
        gemm_bt<2><<<g768, 256, 0, stream>>>(S0, WoB, DD, DD, DD, S1, nullptr,
                                             nullptr, nullptr, x, nullptr);  // h->S1
        ln_stats_k<__hip_bfloat16><<<LN_GRID, 256, 0, stream>>>(S1, meanB, rstdB);
        mix_k<__hip_bfloat16, 2><<<MIX_GRID, 256, 0, stream>>>(S1, meanB, rstdB, ln2_g, ln2_b,
                                                               cmu_k, nullptr, cmu_r,
                                                               S0, nullptr, S2);
        // gate as fp32 parked in d_out (each MODE-6 block reads only its own tile)
        gemm_bt<7><<<g768, 256, 0, stream>>>(S2, CrB, DD, DD, DD, nullptr, out,
                                             nullptr, nullptr, nullptr, nullptr);
        gemm_bt<3><<<gCk, 256, 0, stream>>>(S0, CkB, DD, DD, HIDN,
                                            S2, nullptr, nullptr, nullptr, nullptr, nullptr);
        gemm_bt<6><<<g768, 256, 0, stream>>>(S2, CvB, HIDN, HIDN, DD,
                                             nullptr, out, nullptr, S1, x, out);
    } else {
        // 5-slot fallback: legacy verified schedule
        gemm_qkv<<<gqkv2, 256, 0, stream>>>(S0, S1, nullptr, WkB, WvB, nullptr,
                                            S3, S4, nullptr);       // k->S3, v->S4
        gemm_bt<1><<<g768, 256, 0, stream>>>(S2, WrB, DD, DD, DD, S0, nullptr,
                                             nullptr, nullptr, nullptr, nullptr); // r->S0
        wkv_passA<<<gwkv, 192, 0, stream>>>(w_log, S3, S4, SAb, SBb, SPb);
        wkv_scanj<<<SCANJ_GRID, 256, 0, stream>>>(w_log, SAb, SBb, SPb);
        wkv_passB<<<gwkv, 192, 0, stream>>>(w_log, u, S3, S4, S0, S1, SAb, SBb, SPb); // rw->S1
        gemm_bt<2><<<g768, 256, 0, stream>>>(S1, WoB, DD, DD, DD, S2, nullptr,
                                             nullptr, nullptr, x, nullptr);       // h->S2
        ln_stats_k<__hip_bfloat16><<<LN_GRID, 256, 0, stream>>>(S2, meanB, rstdB);
        mix_k<__hip_bfloat16, 2><<<MIX_GRID, 256, 0, stream>>>(S2, meanB, rstdB, ln2_g, ln2_b,
                                                               cmu_k, nullptr, cmu_r,
                                                               S0, nullptr, S3);
        gemm_bt<1><<<g768, 256, 0, stream>>>(S3, CrB, DD, DD, DD, S1, nullptr,
                                             nullptr, nullptr, nullptr, nullptr); // cr->S1
        __hip_bfloat16* kk = S3;  // FFN in two 1536-wide halves (kk in S3+S4)
        gemm_bt<3><<<g1536, 256, 0, stream>>>(S0, CkB, DD, DD, HHALF,
                                              kk, nullptr, nullptr, nullptr, nullptr, nullptr);
        gemm_bt<4><<<g768, 256, 0, stream>>>(kk, CvB, HHALF, HIDN, DD,
                                             nullptr, out, S1, S2, x, nullptr);
        gemm_bt<3><<<g1536, 256, 0, stream>>>(S0, CkB + (size_t)HHALF * DD, DD, DD, HHALF,
                                              kk, nullptr, nullptr, nullptr, nullptr, nullptr);
        gemm_bt<5><<<g768, 256, 0, stream>>>(kk, CvB + HHALF, HHALF, HIDN, DD,
                                             nullptr, out, S1, nullptr, nullptr, nullptr);
    }
}